// Round 14
// baseline (340.417 us; speedup 1.0000x reference)
//
#include <hip/hip_runtime.h>
#include <hip/hip_bf16.h>

typedef unsigned short u16;
typedef unsigned int u32;
typedef short s16x8 __attribute__((ext_vector_type(8)));
typedef float f32x4 __attribute__((ext_vector_type(4)));
typedef float f32x16 __attribute__((ext_vector_type(16)));
typedef u16 u16x4 __attribute__((ext_vector_type(4)));
typedef u32 u32x4 __attribute__((ext_vector_type(4)));

#define D_MODEL 1024
#define NHEAD 16
#define DK 64
#define B_ 4
#define N_ 2048
#define M_TOT (B_ * N_) /* 8192 */
#define QBLK 128
#define KVBLK 64
#define SCALE2 0.1803368801111137f /* 0.125 * log2(e) */
#define FRAG_PER_BH 131072 /* N_*DK elems per (b,h) */

__device__ __forceinline__ u16 f2b(float x) {
  __hip_bfloat16 h = __float2bfloat16(x);
  return __builtin_bit_cast(u16, h);
}

__device__ __forceinline__ u32 cvtpk(float lo, float hi) {
  u32 r;
  asm("v_cvt_pk_bf16_f32 %0, %1, %2" : "=v"(r) : "v"(lo), "v"(hi));
  return r;
}

__device__ __forceinline__ void gload_lds16(const void* gp, void* lp) {
  __builtin_amdgcn_global_load_lds(
      (const __attribute__((address_space(1))) unsigned int*)gp,
      (__attribute__((address_space(3))) unsigned int*)lp, 16, 0, 0);
}

// ---------------- elementwise f32 -> bf16 ----------------
__global__ __launch_bounds__(256) void cvt_f32_bf16(const float* __restrict__ x,
                                                    u16* __restrict__ y, int n4) {
  int i = blockIdx.x * 256 + threadIdx.x;
  if (i < n4) {
    f32x4 v = *(const f32x4*)(x + (size_t)i * 4);
    u16x4 o;
    o[0] = f2b(v[0]); o[1] = f2b(v[1]); o[2] = f2b(v[2]); o[3] = f2b(v[3]);
    *(u16x4*)(y + (size_t)i * 4) = o;
  }
}

// ---------------- padding mask -> float bias (0 or -inf) ----------------
__global__ __launch_bounds__(256) void mask_bias(const int* __restrict__ mask,
                                                 float* __restrict__ Mb, int n) {
  int i = blockIdx.x * 256 + threadIdx.x;
  if (i < n) Mb[i] = mask[i] ? 0.f : -INFINITY;
}

// ---------------- W (f32, [K][N]) -> W^T (bf16, [N][K]) ----------------
__global__ __launch_bounds__(256) void wtrans(const float* __restrict__ W,
                                              u16* __restrict__ Wt) {
  __shared__ float tile[32][33];
  int bi = blockIdx.y, bj = blockIdx.x;
  int tx = threadIdx.x & 31, ty = threadIdx.x >> 5; // 32 x 8
#pragma unroll
  for (int r = 0; r < 4; ++r)
    tile[ty + r * 8][tx] = W[(size_t)(bi * 32 + ty + r * 8) * D_MODEL + bj * 32 + tx];
  __syncthreads();
#pragma unroll
  for (int r = 0; r < 4; ++r)
    Wt[(size_t)(bj * 32 + ty + r * 8) * D_MODEL + bi * 32 + tx] = f2b(tile[tx][ty + r * 8]);
}

// ------------- K [B,N,H*64] -> fragment-major Kf -------------
__global__ __launch_bounds__(256) void kfrag_k(const u16* __restrict__ Kp,
                                               u16* __restrict__ Kf) {
  __shared__ __align__(16) u16 tile[64][72];
  int kv0 = blockIdx.x * 64, h = blockIdx.y, b = blockIdx.z;
  int tid = threadIdx.x;
#pragma unroll
  for (int it = 0; it < 2; ++it) {
    int r = it * 32 + (tid >> 3), c8 = (tid & 7) * 8;
    *(s16x8*)&tile[r][c8] =
        *(const s16x8*)&Kp[(size_t)(b * N_ + kv0 + r) * D_MODEL + h * DK + c8];
  }
  __syncthreads();
  int w = tid >> 6, lane = tid & 63;
  int q32 = lane & 31, hi = lane >> 5;
  size_t kfb = (size_t)(b * NHEAD + h) * FRAG_PER_BH;
#pragma unroll
  for (int kv32L = 0; kv32L < 2; ++kv32L) {
    s16x8 v = *(const s16x8*)&tile[kv32L * 32 + q32][w * 16 + hi * 8];
    *(s16x8*)&Kf[kfb + ((size_t)(kv0 / 32 + kv32L) * 4 + w) * 512 + lane * 8] = v;
  }
}

// ------------- V [B,N,H*64] -> fragment-major Vf -------------
__global__ __launch_bounds__(256) void vfrag_k(const u16* __restrict__ Vp,
                                               u16* __restrict__ Vf) {
  __shared__ __align__(16) u16 tile[64][72];
  int n0 = blockIdx.x * 64, h = blockIdx.y, b = blockIdx.z;
  int tid = threadIdx.x;
#pragma unroll
  for (int it = 0; it < 2; ++it) {
    int r = it * 32 + (tid >> 3), c8 = (tid & 7) * 8;
    *(s16x8*)&tile[r][c8] =
        *(const s16x8*)&Vp[(size_t)(b * N_ + n0 + r) * D_MODEL + h * DK + c8];
  }
  __syncthreads();
  int w = tid >> 6, lane = tid & 63; // w = local kv16 index
  int d32 = lane & 31, hi = lane >> 5;
  size_t vfb = (size_t)(b * NHEAD + h) * FRAG_PER_BH;
#pragma unroll
  for (int d0 = 0; d0 < 2; ++d0) {
    s16x8 vv;
#pragma unroll
    for (int e = 0; e < 8; ++e)
      vv[e] = (short)tile[w * 16 + hi * 8 + e][d0 * 32 + d32];
    *(s16x8*)&Vf[vfb + ((size_t)(n0 / 16 + w) * 2 + d0) * 512 + lane * 8] = vv;
  }
}

// ------------- GEMM: C[M,N] = A[M,K](bf16) * Bt[N,K](bf16)^T -------------
template <bool OUT_F32>
__global__ __launch_bounds__(256) void gemm_bt(const u16* __restrict__ A,
                                               const u16* __restrict__ Bt,
                                               float* __restrict__ Cf,
                                               u16* __restrict__ Cb,
                                               int M, int N, int K) {
  __shared__ __align__(16) u16 Atile[128 * 32];
  __shared__ __align__(16) u16 Btile[128 * 32];
  int tid = threadIdx.x;
  int w = tid >> 6, lane = tid & 63;
  int g = lane >> 4, c = lane & 15;
  int wr = w >> 1, wc = w & 1;
  int bi = blockIdx.y, bj = blockIdx.x;
  const int rowA0 = bi * 128, rowB0 = bj * 128;

  const f32x4 fzero = {0.f, 0.f, 0.f, 0.f};
  f32x4 acc[4][4];
#pragma unroll
  for (int m = 0; m < 4; ++m)
#pragma unroll
    for (int n = 0; n < 4; ++n) acc[m][n] = fzero;

  for (int k0 = 0; k0 < K; k0 += 32) {
#pragma unroll
    for (int cc = 0; cc < 2; ++cc) {
      int li = w * 2 + cc;
      const u16* ga = A + (size_t)(rowA0 + li * 16 + (lane >> 2)) * K + k0 + (lane & 3) * 8;
      gload_lds16(ga, &Atile[li * 512]);
      const u16* gb = Bt + (size_t)(rowB0 + li * 16 + (lane >> 2)) * K + k0 + (lane & 3) * 8;
      gload_lds16(gb, &Btile[li * 512]);
    }
    __syncthreads();
    s16x8 af[4], bfr[4];
#pragma unroll
    for (int m = 0; m < 4; ++m)
      af[m] = *(const s16x8*)&Atile[(wr * 64 + m * 16 + c) * 32 + g * 8];
#pragma unroll
    for (int n = 0; n < 4; ++n)
      bfr[n] = *(const s16x8*)&Btile[(wc * 64 + n * 16 + c) * 32 + g * 8];
#pragma unroll
    for (int m = 0; m < 4; ++m)
#pragma unroll
      for (int n = 0; n < 4; ++n)
        acc[m][n] = __builtin_amdgcn_mfma_f32_16x16x32_bf16(af[m], bfr[n], acc[m][n], 0, 0, 0);
    __syncthreads();
  }
#pragma unroll
  for (int m = 0; m < 4; ++m)
#pragma unroll
    for (int n = 0; n < 4; ++n)
#pragma unroll
      for (int r = 0; r < 4; ++r) {
        int row = rowA0 + wr * 64 + m * 16 + g * 4 + r;
        int col = rowB0 + wc * 64 + n * 16 + c;
        size_t idx = (size_t)row * N + col;
        if (OUT_F32) Cf[idx] = acc[m][n][r];
        else Cb[idx] = f2b(acc[m][n][r]);
      }
}

#define MAX4(a, b, c, d) fmaxf(fmaxf(a, b), fmaxf(c, d))

// ------------- causal flash attention: 32x32 MFMA, fragment-major K/V -----
// R13 structure + (a) 1024-block grid (3 blocks/CU, heavy-first, XCD-local)
// (b) pointer-bump addressing: per-lane frag base + compile-time offsets,
// bumped by a constant per tile -- kills the per-load mad64 chains.
__global__ __launch_bounds__(256) void attn_fwd(const u16* __restrict__ Qp,
                                                const u16* __restrict__ Kf,
                                                const u16* __restrict__ Vf,
                                                const float* __restrict__ Mb,
                                                u16* __restrict__ Out) {
  int bid = blockIdx.x;
  int xcd = bid & 7;
  int inner = bid >> 3;       // 0..127
  int j = inner >> 4;         // head-within-XCD 0..7
  int qt = 15 - (inner & 15); // heavy tiles first
  int bh = xcd * 8 + j;       // 0..63
  int b = bh >> 4, h = bh & 15;
  int tid = threadIdx.x, w = tid >> 6, lane = tid & 63;
  int q32 = lane & 31, hi = lane >> 5;
  int hi8 = hi * 8, hi4 = hi * 4;

  int q0 = qt * QBLK;
  int wq0 = q0 + w * 32; // this wave's first q row
  int ntw = wq0 / KVBLK + 1;
  int qq = wq0 + q32;

  // per-lane bumped base pointers (all step offsets are compile-time imms)
  const u16* kfp = Kf + (size_t)(b * NHEAD + h) * FRAG_PER_BH + lane * 8;
  const u16* vfp = Vf + (size_t)(b * NHEAD + h) * FRAG_PER_BH + lane * 8;
  const float* mpl = Mb + (size_t)b * N_ + hi4;

  // Q (B-operand): lane holds Q[wq0+q32][kk*16+hi*8+e]
  s16x8 qf[4];
  {
    const u16* qb2 = Qp + (size_t)(b * N_ + wq0 + q32) * D_MODEL + h * DK;
#pragma unroll
    for (int kk = 0; kk < 4; ++kk) qf[kk] = *(const s16x8*)(qb2 + kk * 16 + hi8);
  }

  const f32x16 fz16 = {0.f, 0.f, 0.f, 0.f, 0.f, 0.f, 0.f, 0.f,
                       0.f, 0.f, 0.f, 0.f, 0.f, 0.f, 0.f, 0.f};
  f32x16 oacc[2];
  oacc[0] = fz16; oacc[1] = fz16;
  float mr = -1e30f, lr = 0.f; // per-lane (q=q32); lr = half-row partial

  auto loadk = [&](s16x8(&kf)[2][4], const u16* kp) {
#pragma unroll
    for (int n = 0; n < 2; ++n)
#pragma unroll
      for (int kk = 0; kk < 4; ++kk)
        kf[n][kk] = *(const s16x8*)(kp + (n * 4 + kk) * 512);
  };

  auto step = [&](s16x8(&kc)[2][4], s16x8(&kn)[2][4], int t) {
    int kv0 = t * KVBLK;
    if (t + 1 < ntw) loadk(kn, kfp + 4096); // prefetch next tile (imm offsets)
    // V (B-operand) for THIS tile (imm offsets off vfp)
    s16x8 vf[2][2][2];
#pragma unroll
    for (int n = 0; n < 2; ++n)
#pragma unroll
      for (int kk2 = 0; kk2 < 2; ++kk2)
#pragma unroll
        for (int d0 = 0; d0 < 2; ++d0)
          vf[n][kk2][d0] = *(const s16x8*)(vfp + ((n * 2 + kk2) * 2 + d0) * 512);
    f32x4 mbv[2][4];
#pragma unroll
    for (int n = 0; n < 2; ++n)
#pragma unroll
      for (int jj = 0; jj < 4; ++jj)
        mbv[n][jj] = *(const f32x4*)(mpl + n * 32 + jj * 8);

    // ---- S^T = K Q^T : st[n][r] = S[q=wq0+q32][kv=kv0+n*32+(r&3)+8*(r>>2)+4hi]
    f32x16 st[2];
#pragma unroll
    for (int n = 0; n < 2; ++n) {
      f32x16 a = fz16;
      a = __builtin_amdgcn_mfma_f32_32x32x16_bf16(kc[n][0], qf[0], a, 0, 0, 0);
      a = __builtin_amdgcn_mfma_f32_32x32x16_bf16(kc[n][1], qf[1], a, 0, 0, 0);
      a = __builtin_amdgcn_mfma_f32_32x32x16_bf16(kc[n][2], qf[2], a, 0, 0, 0);
      a = __builtin_amdgcn_mfma_f32_32x32x16_bf16(kc[n][3], qf[3], a, 0, 0, 0);
      st[n] = a;
    }

    // ---- scale + padding bias + causal mask
    bool diag = (kv0 + KVBLK - 1 > wq0);
#pragma unroll
    for (int n = 0; n < 2; ++n)
#pragma unroll
      for (int r = 0; r < 16; ++r) {
        float v = fmaf(st[n][r], SCALE2, mbv[n][r >> 2][r & 3]);
        if (diag) {
          int kv = kv0 + n * 32 + (r & 3) + 8 * (r >> 2) + hi4;
          v = (kv > qq) ? -INFINITY : v;
        }
        st[n][r] = v;
      }
    // per-lane max over its 32 values (tree)
    float a0 = MAX4(st[0][0], st[0][1], st[0][2], st[0][3]);
    float a1 = MAX4(st[0][4], st[0][5], st[0][6], st[0][7]);
    float a2 = MAX4(st[0][8], st[0][9], st[0][10], st[0][11]);
    float a3 = MAX4(st[0][12], st[0][13], st[0][14], st[0][15]);
    float b0 = MAX4(st[1][0], st[1][1], st[1][2], st[1][3]);
    float b1 = MAX4(st[1][4], st[1][5], st[1][6], st[1][7]);
    float b2 = MAX4(st[1][8], st[1][9], st[1][10], st[1][11]);
    float b3 = MAX4(st[1][12], st[1][13], st[1][14], st[1][15]);
    float pmax = fmaxf(MAX4(a0, a1, a2, a3), MAX4(b0, b1, b2, b3));

    // ---- defer-max rescale (T13); al identical for lane pair (q, q+32)
    if (__any(pmax > mr + 8.f)) {
      float pm2 = fmaxf(pmax, __shfl_xor(pmax, 32));
      float mnew = fmaxf(mr, pm2);
      float al = exp2f(mr - mnew);
      mr = mnew;
      lr *= al;
#pragma unroll
      for (int r = 0; r < 16; ++r) {
        float alT = __shfl(al, (r & 3) + 8 * (r >> 2) + hi4);
        oacc[0][r] *= alT;
        oacc[1][r] *= alT;
      }
    }

    // ---- p = exp2(s - m) (lane-local sum), pack -> PV A-frags (T12)
    s16x8 pa[2][2];
#pragma unroll
    for (int n = 0; n < 2; ++n) {
#pragma unroll
      for (int r = 0; r < 16; ++r) st[n][r] = exp2f(st[n][r] - mr);
      float s01 = st[n][0] + st[n][1], s23 = st[n][2] + st[n][3];
      float s45 = st[n][4] + st[n][5], s67 = st[n][6] + st[n][7];
      float s89 = st[n][8] + st[n][9], sab = st[n][10] + st[n][11];
      float scd = st[n][12] + st[n][13], sef = st[n][14] + st[n][15];
      lr += ((s01 + s23) + (s45 + s67)) + ((s89 + sab) + (scd + sef));
      u32 x0 = cvtpk(st[n][0], st[n][1]);
      u32 x1 = cvtpk(st[n][2], st[n][3]);
      u32 x2 = cvtpk(st[n][4], st[n][5]);
      u32 x3 = cvtpk(st[n][6], st[n][7]);
      auto sA = __builtin_amdgcn_permlane32_swap(x0, x2, false, false);
      auto sB = __builtin_amdgcn_permlane32_swap(x1, x3, false, false);
      u32x4 w0 = {sA[0], sB[0], sA[1], sB[1]};
      pa[n][0] = __builtin_bit_cast(s16x8, w0);
      u32 x4 = cvtpk(st[n][8], st[n][9]);
      u32 x5 = cvtpk(st[n][10], st[n][11]);
      u32 x6 = cvtpk(st[n][12], st[n][13]);
      u32 x7 = cvtpk(st[n][14], st[n][15]);
      auto sC = __builtin_amdgcn_permlane32_swap(x4, x6, false, false);
      auto sD = __builtin_amdgcn_permlane32_swap(x5, x7, false, false);
      u32x4 w1 = {sC[0], sD[0], sC[1], sD[1]};
      pa[n][1] = __builtin_bit_cast(s16x8, w1);
    }

    // ---- O += P * V (in-register A-operand)
#pragma unroll
    for (int n = 0; n < 2; ++n)
#pragma unroll
      for (int kk2 = 0; kk2 < 2; ++kk2)
#pragma unroll
        for (int d0 = 0; d0 < 2; ++d0)
          oacc[d0] = __builtin_amdgcn_mfma_f32_32x32x16_bf16(pa[n][kk2], vf[n][kk2][d0], oacc[d0], 0, 0, 0);

    // bump bases for next tile (uniform adds)
    kfp += 4096;
    vfp += 4096;
    mpl += KVBLK;
  };

  s16x8 kA[2][4], kB[2][4];
  loadk(kA, kfp);
  for (int t = 0; t < ntw; t += 2) {
    step(kA, kB, t);
    if (t + 1 < ntw) step(kB, kA, t + 1);
  }

  // ---- epilogue: complete l across lane pair, normalize + store
  lr += __shfl_xor(lr, 32);
#pragma unroll
  for (int r = 0; r < 16; ++r) {
    int qoff = (r & 3) + 8 * (r >> 2) + hi4;
    float lq = __shfl(lr, qoff);
    float inv = lq > 0.f ? 1.f / lq : 0.f;
    size_t base = (size_t)(b * N_ + wq0 + qoff) * D_MODEL + h * DK + q32;
    Out[base] = f2b(oacc[0][r] * inv);
    Out[base + 32] = f2b(oacc[1][r] * inv);
  }
}

extern "C" void kernel_launch(void* const* d_in, const int* in_sizes, int n_in,
                              void* d_out, int out_size, void* d_ws, size_t ws_size,
                              hipStream_t stream) {
  const float* q = (const float*)d_in[0];
  const float* k = (const float*)d_in[1];
  const float* v = (const float*)d_in[2];
  const int* mask = (const int*)d_in[3];
  const float* Wq = (const float*)d_in[4];
  const float* Wk = (const float*)d_in[5];
  const float* Wv = (const float*)d_in[6];
  const float* Wo = (const float*)d_in[7];
  float* out = (float*)d_out;

  char* ws = (char*)d_ws;
  const size_t SZ = (size_t)M_TOT * D_MODEL * 2; // 16 MiB per bf16 [8192,1024]
  u16* qb = (u16*)ws;            // cvt(q) -> Q GEMM; then Vp; then attn_out
  u16* kb = (u16*)(ws + SZ);     // cvt(k) -> K GEMM; then Kf
  u16* vb = (u16*)(ws + 2 * SZ); // cvt(v) -> V GEMM; then Vf
  u16* Qp = (u16*)(ws + 3 * SZ);
  u16* Kp = (u16*)(ws + 4 * SZ);
  u16* Wqt = (u16*)(ws + 5 * SZ);
  u16* Wkt = Wqt + 1024 * 1024;
  u16* Wvt = Wkt + 1024 * 1024;
  u16* Wot = Wvt + 1024 * 1024;
  float* Mb = (float*)(Wot + 1024 * 1024);
  // lifetime-disjoint aliases:
  u16* Vp = qb;       // qb dead after Q GEMM; Vp dead after vfrag
  u16* Kf = kb;       // kb dead after K GEMM
  u16* Vf = vb;       // vb dead after V GEMM
  u16* attn_out = qb; // Vp dead after vfrag

  int n4 = M_TOT * D_MODEL / 4;
  cvt_f32_bf16<<<n4 / 256, 256, 0, stream>>>(q, qb, n4);
  cvt_f32_bf16<<<n4 / 256, 256, 0, stream>>>(k, kb, n4);
  cvt_f32_bf16<<<n4 / 256, 256, 0, stream>>>(v, vb, n4);
  mask_bias<<<(B_ * N_ + 255) / 256, 256, 0, stream>>>(mask, Mb, B_ * N_);
  dim3 wg(32, 32);
  wtrans<<<wg, 256, 0, stream>>>(Wq, Wqt);
  wtrans<<<wg, 256, 0, stream>>>(Wk, Wkt);
  wtrans<<<wg, 256, 0, stream>>>(Wv, Wvt);
  wtrans<<<wg, 256, 0, stream>>>(Wo, Wot);
  dim3 gg(D_MODEL / 128, M_TOT / 128);
  gemm_bt<false><<<gg, 256, 0, stream>>>(qb, Wqt, nullptr, Qp, M_TOT, D_MODEL, D_MODEL);
  gemm_bt<false><<<gg, 256, 0, stream>>>(kb, Wkt, nullptr, Kp, M_TOT, D_MODEL, D_MODEL);
  gemm_bt<false><<<gg, 256, 0, stream>>>(vb, Wvt, nullptr, Vp, M_TOT, D_MODEL, D_MODEL);
  dim3 fg(N_ / 64, NHEAD, B_);
  kfrag_k<<<fg, 256, 0, stream>>>(Kp, Kf);
  vfrag_k<<<fg, 256, 0, stream>>>(Vp, Vf);
  attn_fwd<<<1024, 256, 0, stream>>>(Qp, Kf, Vf, Mb, attn_out);
  gemm_bt<true><<<gg, 256, 0, stream>>>(attn_out, Wot, out, nullptr, M_TOT, D_MODEL, D_MODEL);
}

// Round 15
// 287.079 us; speedup vs baseline: 1.1858x; 1.1858x over previous
//
#include <hip/hip_runtime.h>
#include <hip/hip_bf16.h>

typedef unsigned short u16;
typedef unsigned int u32;
typedef short s16x8 __attribute__((ext_vector_type(8)));
typedef float f32x4 __attribute__((ext_vector_type(4)));
typedef float f32x16 __attribute__((ext_vector_type(16)));
typedef u16 u16x4 __attribute__((ext_vector_type(4)));
typedef u32 u32x4 __attribute__((ext_vector_type(4)));

#define D_MODEL 1024
#define NHEAD 16
#define DK 64
#define B_ 4
#define N_ 2048
#define M_TOT (B_ * N_) /* 8192 */
#define QBLK 128
#define KVBLK 64
#define SCALE2 0.1803368801111137f /* 0.125 * log2(e) */
#define FRAG_PER_BH 131072 /* N_*DK elems per (b,h) */
#define EX2(x) __builtin_amdgcn_exp2f(x) /* raw v_exp_f32 */

__device__ __forceinline__ u16 f2b(float x) {
  __hip_bfloat16 h = __float2bfloat16(x);
  return __builtin_bit_cast(u16, h);
}

__device__ __forceinline__ u32 cvtpk(float lo, float hi) {
  u32 r;
  asm("v_cvt_pk_bf16_f32 %0, %1, %2" : "=v"(r) : "v"(lo), "v"(hi));
  return r;
}

__device__ __forceinline__ void gload_lds16(const void* gp, void* lp) {
  __builtin_amdgcn_global_load_lds(
      (const __attribute__((address_space(1))) unsigned int*)gp,
      (__attribute__((address_space(3))) unsigned int*)lp, 16, 0, 0);
}

// ---------------- elementwise f32 -> bf16 ----------------
__global__ __launch_bounds__(256) void cvt_f32_bf16(const float* __restrict__ x,
                                                    u16* __restrict__ y, int n4) {
  int i = blockIdx.x * 256 + threadIdx.x;
  if (i < n4) {
    f32x4 v = *(const f32x4*)(x + (size_t)i * 4);
    u16x4 o;
    o[0] = f2b(v[0]); o[1] = f2b(v[1]); o[2] = f2b(v[2]); o[3] = f2b(v[3]);
    *(u16x4*)(y + (size_t)i * 4) = o;
  }
}

// ---------------- padding mask -> float bias (0 or -inf) ----------------
__global__ __launch_bounds__(256) void mask_bias(const int* __restrict__ mask,
                                                 float* __restrict__ Mb, int n) {
  int i = blockIdx.x * 256 + threadIdx.x;
  if (i < n) Mb[i] = mask[i] ? 0.f : -INFINITY;
}

// ---------------- W (f32, [K][N]) -> W^T (bf16, [N][K]) ----------------
__global__ __launch_bounds__(256) void wtrans(const float* __restrict__ W,
                                              u16* __restrict__ Wt) {
  __shared__ float tile[32][33];
  int bi = blockIdx.y, bj = blockIdx.x;
  int tx = threadIdx.x & 31, ty = threadIdx.x >> 5; // 32 x 8
#pragma unroll
  for (int r = 0; r < 4; ++r)
    tile[ty + r * 8][tx] = W[(size_t)(bi * 32 + ty + r * 8) * D_MODEL + bj * 32 + tx];
  __syncthreads();
#pragma unroll
  for (int r = 0; r < 4; ++r)
    Wt[(size_t)(bj * 32 + ty + r * 8) * D_MODEL + bi * 32 + tx] = f2b(tile[tx][ty + r * 8]);
}

// ------------- K [B,N,H*64] -> fragment-major Kf -------------
__global__ __launch_bounds__(256) void kfrag_k(const u16* __restrict__ Kp,
                                               u16* __restrict__ Kf) {
  __shared__ __align__(16) u16 tile[64][72];
  int kv0 = blockIdx.x * 64, h = blockIdx.y, b = blockIdx.z;
  int tid = threadIdx.x;
#pragma unroll
  for (int it = 0; it < 2; ++it) {
    int r = it * 32 + (tid >> 3), c8 = (tid & 7) * 8;
    *(s16x8*)&tile[r][c8] =
        *(const s16x8*)&Kp[(size_t)(b * N_ + kv0 + r) * D_MODEL + h * DK + c8];
  }
  __syncthreads();
  int w = tid >> 6, lane = tid & 63;
  int q32 = lane & 31, hi = lane >> 5;
  size_t kfb = (size_t)(b * NHEAD + h) * FRAG_PER_BH;
#pragma unroll
  for (int kv32L = 0; kv32L < 2; ++kv32L) {
    s16x8 v = *(const s16x8*)&tile[kv32L * 32 + q32][w * 16 + hi * 8];
    *(s16x8*)&Kf[kfb + ((size_t)(kv0 / 32 + kv32L) * 4 + w) * 512 + lane * 8] = v;
  }
}

// ------------- V [B,N,H*64] -> fragment-major Vf -------------
__global__ __launch_bounds__(256) void vfrag_k(const u16* __restrict__ Vp,
                                               u16* __restrict__ Vf) {
  __shared__ __align__(16) u16 tile[64][72];
  int n0 = blockIdx.x * 64, h = blockIdx.y, b = blockIdx.z;
  int tid = threadIdx.x;
#pragma unroll
  for (int it = 0; it < 2; ++it) {
    int r = it * 32 + (tid >> 3), c8 = (tid & 7) * 8;
    *(s16x8*)&tile[r][c8] =
        *(const s16x8*)&Vp[(size_t)(b * N_ + n0 + r) * D_MODEL + h * DK + c8];
  }
  __syncthreads();
  int w = tid >> 6, lane = tid & 63; // w = local kv16 index
  int d32 = lane & 31, hi = lane >> 5;
  size_t vfb = (size_t)(b * NHEAD + h) * FRAG_PER_BH;
#pragma unroll
  for (int d0 = 0; d0 < 2; ++d0) {
    s16x8 vv;
#pragma unroll
    for (int e = 0; e < 8; ++e)
      vv[e] = (short)tile[w * 16 + hi * 8 + e][d0 * 32 + d32];
    *(s16x8*)&Vf[vfb + ((size_t)(n0 / 16 + w) * 2 + d0) * 512 + lane * 8] = vv;
  }
}

// ------------- GEMM: C[M,N] = A[M,K](bf16) * Bt[N,K](bf16)^T -------------
template <bool OUT_F32>
__global__ __launch_bounds__(256) void gemm_bt(const u16* __restrict__ A,
                                               const u16* __restrict__ Bt,
                                               float* __restrict__ Cf,
                                               u16* __restrict__ Cb,
                                               int M, int N, int K) {
  __shared__ __align__(16) u16 Atile[128 * 32];
  __shared__ __align__(16) u16 Btile[128 * 32];
  int tid = threadIdx.x;
  int w = tid >> 6, lane = tid & 63;
  int g = lane >> 4, c = lane & 15;
  int wr = w >> 1, wc = w & 1;
  int bi = blockIdx.y, bj = blockIdx.x;
  const int rowA0 = bi * 128, rowB0 = bj * 128;

  const f32x4 fzero = {0.f, 0.f, 0.f, 0.f};
  f32x4 acc[4][4];
#pragma unroll
  for (int m = 0; m < 4; ++m)
#pragma unroll
    for (int n = 0; n < 4; ++n) acc[m][n] = fzero;

  for (int k0 = 0; k0 < K; k0 += 32) {
#pragma unroll
    for (int cc = 0; cc < 2; ++cc) {
      int li = w * 2 + cc;
      const u16* ga = A + (size_t)(rowA0 + li * 16 + (lane >> 2)) * K + k0 + (lane & 3) * 8;
      gload_lds16(ga, &Atile[li * 512]);
      const u16* gb = Bt + (size_t)(rowB0 + li * 16 + (lane >> 2)) * K + k0 + (lane & 3) * 8;
      gload_lds16(gb, &Btile[li * 512]);
    }
    __syncthreads();
    s16x8 af[4], bfr[4];
#pragma unroll
    for (int m = 0; m < 4; ++m)
      af[m] = *(const s16x8*)&Atile[(wr * 64 + m * 16 + c) * 32 + g * 8];
#pragma unroll
    for (int n = 0; n < 4; ++n)
      bfr[n] = *(const s16x8*)&Btile[(wc * 64 + n * 16 + c) * 32 + g * 8];
#pragma unroll
    for (int m = 0; m < 4; ++m)
#pragma unroll
      for (int n = 0; n < 4; ++n)
        acc[m][n] = __builtin_amdgcn_mfma_f32_16x16x32_bf16(af[m], bfr[n], acc[m][n], 0, 0, 0);
    __syncthreads();
  }
#pragma unroll
  for (int m = 0; m < 4; ++m)
#pragma unroll
    for (int n = 0; n < 4; ++n)
#pragma unroll
      for (int r = 0; r < 4; ++r) {
        int row = rowA0 + wr * 64 + m * 16 + g * 4 + r;
        int col = rowB0 + wc * 64 + n * 16 + c;
        size_t idx = (size_t)row * N + col;
        if (OUT_F32) Cf[idx] = acc[m][n][r];
        else Cb[idx] = f2b(acc[m][n][r]);
      }
}

#define MAX4(a, b, c, d) fmaxf(fmaxf(a, b), fmaxf(c, d))

// ------------- causal flash attention: 32x32 MFMA, fragment-major K/V -----
// R13 structure (paired q-tiles {15-p,p}, XCD-local heads, zero LDS, no
// barriers, in-register softmax via cvt_pk+permlane32_swap, defer-max,
// K reg dbuf prefetch) + R14's pointer-bump addressing + raw v_exp_f32.
__global__ __launch_bounds__(256) void attn_fwd(const u16* __restrict__ Qp,
                                                const u16* __restrict__ Kf,
                                                const u16* __restrict__ Vf,
                                                const float* __restrict__ Mb,
                                                u16* __restrict__ Out) {
  int bid = blockIdx.x;
  int xcd = bid & 7;
  int inner = bid >> 3; // 0..63
  int j = inner >> 3;   // head-within-XCD 0..7
  int pair = inner & 7; // 0..7
  int bh = xcd * 8 + j; // 0..63
  int b = bh >> 4, h = bh & 15;
  int tid = threadIdx.x, w = tid >> 6, lane = tid & 63;
  int q32 = lane & 31, hi = lane >> 5;
  int hi8 = hi * 8, hi4 = hi * 4;

  const u16* kfb0 = Kf + (size_t)(b * NHEAD + h) * FRAG_PER_BH + lane * 8;
  const u16* vfb0 = Vf + (size_t)(b * NHEAD + h) * FRAG_PER_BH + lane * 8;
  const float* mb0 = Mb + (size_t)b * N_ + hi4;

  const f32x16 fz16 = {0.f, 0.f, 0.f, 0.f, 0.f, 0.f, 0.f, 0.f,
                       0.f, 0.f, 0.f, 0.f, 0.f, 0.f, 0.f, 0.f};

#pragma unroll 1
  for (int ph = 0; ph < 2; ++ph) {
    int qt = ph ? pair : 15 - pair;
    int q0 = qt * QBLK;
    int wq0 = q0 + w * 32; // this wave's first q row
    int ntw = wq0 / KVBLK + 1;
    int qq = wq0 + q32;

    // per-phase bumped base pointers (step offsets are compile-time imms)
    const u16* kfp = kfb0;
    const u16* vfp = vfb0;
    const float* mpl = mb0;

    // Q (B-operand): lane holds Q[wq0+q32][kk*16+hi*8+e]
    s16x8 qf[4];
    {
      const u16* qb2 = Qp + (size_t)(b * N_ + wq0 + q32) * D_MODEL + h * DK;
#pragma unroll
      for (int kk = 0; kk < 4; ++kk) qf[kk] = *(const s16x8*)(qb2 + kk * 16 + hi8);
    }

    f32x16 oacc[2];
    oacc[0] = fz16; oacc[1] = fz16;
    float mr = -1e30f, lr = 0.f; // per-lane (q=q32); lr = half-row partial

    auto loadk = [&](s16x8(&kf)[2][4], const u16* kp) {
#pragma unroll
      for (int n = 0; n < 2; ++n)
#pragma unroll
        for (int kk = 0; kk < 4; ++kk)
          kf[n][kk] = *(const s16x8*)(kp + (n * 4 + kk) * 512);
    };

    auto step = [&](s16x8(&kc)[2][4], s16x8(&kn)[2][4], int t) {
      int kv0 = t * KVBLK;
      if (t + 1 < ntw) loadk(kn, kfp + 4096); // prefetch next tile
      // V (B-operand) for THIS tile (imm offsets off vfp)
      s16x8 vf[2][2][2];
#pragma unroll
      for (int n = 0; n < 2; ++n)
#pragma unroll
        for (int kk2 = 0; kk2 < 2; ++kk2)
#pragma unroll
          for (int d0 = 0; d0 < 2; ++d0)
            vf[n][kk2][d0] = *(const s16x8*)(vfp + ((n * 2 + kk2) * 2 + d0) * 512);
      f32x4 mbv[2][4];
#pragma unroll
      for (int n = 0; n < 2; ++n)
#pragma unroll
        for (int jj = 0; jj < 4; ++jj)
          mbv[n][jj] = *(const f32x4*)(mpl + n * 32 + jj * 8);

      // ---- S^T = K Q^T
      f32x16 st[2];
#pragma unroll
      for (int n = 0; n < 2; ++n) {
        f32x16 a = fz16;
        a = __builtin_amdgcn_mfma_f32_32x32x16_bf16(kc[n][0], qf[0], a, 0, 0, 0);
        a = __builtin_amdgcn_mfma_f32_32x32x16_bf16(kc[n][1], qf[1], a, 0, 0, 0);
        a = __builtin_amdgcn_mfma_f32_32x32x16_bf16(kc[n][2], qf[2], a, 0, 0, 0);
        a = __builtin_amdgcn_mfma_f32_32x32x16_bf16(kc[n][3], qf[3], a, 0, 0, 0);
        st[n] = a;
      }

      // ---- scale + padding bias + causal mask
      bool diag = (kv0 + KVBLK - 1 > wq0);
#pragma unroll
      for (int n = 0; n < 2; ++n)
#pragma unroll
        for (int r = 0; r < 16; ++r) {
          float v = fmaf(st[n][r], SCALE2, mbv[n][r >> 2][r & 3]);
          if (diag) {
            int kv = kv0 + n * 32 + (r & 3) + 8 * (r >> 2) + hi4;
            v = (kv > qq) ? -INFINITY : v;
          }
          st[n][r] = v;
        }
      // per-lane max over its 32 values (tree)
      float a0 = MAX4(st[0][0], st[0][1], st[0][2], st[0][3]);
      float a1 = MAX4(st[0][4], st[0][5], st[0][6], st[0][7]);
      float a2 = MAX4(st[0][8], st[0][9], st[0][10], st[0][11]);
      float a3 = MAX4(st[0][12], st[0][13], st[0][14], st[0][15]);
      float b0 = MAX4(st[1][0], st[1][1], st[1][2], st[1][3]);
      float b1 = MAX4(st[1][4], st[1][5], st[1][6], st[1][7]);
      float b2 = MAX4(st[1][8], st[1][9], st[1][10], st[1][11]);
      float b3 = MAX4(st[1][12], st[1][13], st[1][14], st[1][15]);
      float pmax = fmaxf(MAX4(a0, a1, a2, a3), MAX4(b0, b1, b2, b3));

      // ---- defer-max rescale (T13); al identical for lane pair (q, q+32)
      if (__any(pmax > mr + 8.f)) {
        float pm2 = fmaxf(pmax, __shfl_xor(pmax, 32));
        float mnew = fmaxf(mr, pm2);
        float al = EX2(mr - mnew);
        mr = mnew;
        lr *= al;
#pragma unroll
        for (int r = 0; r < 16; ++r) {
          float alT = __shfl(al, (r & 3) + 8 * (r >> 2) + hi4);
          oacc[0][r] *= alT;
          oacc[1][r] *= alT;
        }
      }

      // ---- p = exp2(s - m) (raw v_exp_f32), pack -> PV A-frags (T12)
      s16x8 pa[2][2];
#pragma unroll
      for (int n = 0; n < 2; ++n) {
#pragma unroll
        for (int r = 0; r < 16; ++r) st[n][r] = EX2(st[n][r] - mr);
        float s01 = st[n][0] + st[n][1], s23 = st[n][2] + st[n][3];
        float s45 = st[n][4] + st[n][5], s67 = st[n][6] + st[n][7];
        float s89 = st[n][8] + st[n][9], sab = st[n][10] + st[n][11];
        float scd = st[n][12] + st[n][13], sef = st[n][14] + st[n][15];
        lr += ((s01 + s23) + (s45 + s67)) + ((s89 + sab) + (scd + sef));
        u32 x0 = cvtpk(st[n][0], st[n][1]);
        u32 x1 = cvtpk(st[n][2], st[n][3]);
        u32 x2 = cvtpk(st[n][4], st[n][5]);
        u32 x3 = cvtpk(st[n][6], st[n][7]);
        auto sA = __builtin_amdgcn_permlane32_swap(x0, x2, false, false);
        auto sB = __builtin_amdgcn_permlane32_swap(x1, x3, false, false);
        u32x4 w0 = {sA[0], sB[0], sA[1], sB[1]};
        pa[n][0] = __builtin_bit_cast(s16x8, w0);
        u32 x4 = cvtpk(st[n][8], st[n][9]);
        u32 x5 = cvtpk(st[n][10], st[n][11]);
        u32 x6 = cvtpk(st[n][12], st[n][13]);
        u32 x7 = cvtpk(st[n][14], st[n][15]);
        auto sC = __builtin_amdgcn_permlane32_swap(x4, x6, false, false);
        auto sD = __builtin_amdgcn_permlane32_swap(x5, x7, false, false);
        u32x4 w1 = {sC[0], sD[0], sC[1], sD[1]};
        pa[n][1] = __builtin_bit_cast(s16x8, w1);
      }

      // ---- O += P * V (in-register A-operand)
#pragma unroll
      for (int n = 0; n < 2; ++n)
#pragma unroll
        for (int kk2 = 0; kk2 < 2; ++kk2)
#pragma unroll
          for (int d0 = 0; d0 < 2; ++d0)
            oacc[d0] = __builtin_amdgcn_mfma_f32_32x32x16_bf16(pa[n][kk2], vf[n][kk2][d0], oacc[d0], 0, 0, 0);

      // bump bases for next tile (uniform adds)
      kfp += 4096;
      vfp += 4096;
      mpl += KVBLK;
    };

    s16x8 kA[2][4], kB[2][4];
    loadk(kA, kfp);
    for (int t = 0; t < ntw; t += 2) {
      step(kA, kB, t);
      if (t + 1 < ntw) step(kB, kA, t + 1);
    }

    // ---- epilogue: complete l across lane pair, normalize + store
    lr += __shfl_xor(lr, 32);
#pragma unroll
    for (int r = 0; r < 16; ++r) {
      int qoff = (r & 3) + 8 * (r >> 2) + hi4;
      float lq = __shfl(lr, qoff);
      float inv = lq > 0.f ? 1.f / lq : 0.f;
      size_t base = (size_t)(b * N_ + wq0 + qoff) * D_MODEL + h * DK + q32;
      Out[base] = f2b(oacc[0][r] * inv);
      Out[base + 32] = f2b(oacc[1][r] * inv);
    }
  }
}

extern "C" void kernel_launch(void* const* d_in, const int* in_sizes, int n_in,
                              void* d_out, int out_size, void* d_ws, size_t ws_size,
                              hipStream_t stream) {
  const float* q = (const float*)d_in[0];
  const float* k = (const float*)d_in[1];
  const float* v = (const float*)d_in[2];
  const int* mask = (const int*)d_in[3];
  const float* Wq = (const float*)d_in[4];
  const float* Wk = (const float*)d_in[5];
  const float* Wv = (const float*)d_in[6];
  const float* Wo = (const float*)d_in[7];
  float* out = (float*)d_out;

  char* ws = (char*)d_ws;
  const size_t SZ = (size_t)M_TOT * D_MODEL * 2; // 16 MiB per bf16 [8192,1024]
  u16* qb = (u16*)ws;            // cvt(q) -> Q GEMM; then Vp; then attn_out
  u16* kb = (u16*)(ws + SZ);     // cvt(k) -> K GEMM; then Kf
  u16* vb = (u16*)(ws + 2 * SZ); // cvt(v) -> V GEMM; then Vf
  u16* Qp = (u16*)(ws + 3 * SZ);
  u16* Kp = (u16*)(ws + 4 * SZ);
  u16* Wqt = (u16*)(ws + 5 * SZ);
  u16* Wkt = Wqt + 1024 * 1024;
  u16* Wvt = Wkt + 1024 * 1024;
  u16* Wot = Wvt + 1024 * 1024;
  float* Mb = (float*)(Wot + 1024 * 1024);
  // lifetime-disjoint aliases:
  u16* Vp = qb;       // qb dead after Q GEMM; Vp dead after vfrag
  u16* Kf = kb;       // kb dead after K GEMM
  u16* Vf = vb;       // vb dead after V GEMM
  u16* attn_out = qb; // Vp dead after vfrag

  int n4 = M_TOT * D_MODEL / 4;
  cvt_f32_bf16<<<n4 / 256, 256, 0, stream>>>(q, qb, n4);
  cvt_f32_bf16<<<n4 / 256, 256, 0, stream>>>(k, kb, n4);
  cvt_f32_bf16<<<n4 / 256, 256, 0, stream>>>(v, vb, n4);
  mask_bias<<<(B_ * N_ + 255) / 256, 256, 0, stream>>>(mask, Mb, B_ * N_);
  dim3 wg(32, 32);
  wtrans<<<wg, 256, 0, stream>>>(Wq, Wqt);
  wtrans<<<wg, 256, 0, stream>>>(Wk, Wkt);
  wtrans<<<wg, 256, 0, stream>>>(Wv, Wvt);
  wtrans<<<wg, 256, 0, stream>>>(Wo, Wot);
  dim3 gg(D_MODEL / 128, M_TOT / 128);
  gemm_bt<false><<<gg, 256, 0, stream>>>(qb, Wqt, nullptr, Qp, M_TOT, D_MODEL, D_MODEL);
  gemm_bt<false><<<gg, 256, 0, stream>>>(kb, Wkt, nullptr, Kp, M_TOT, D_MODEL, D_MODEL);
  gemm_bt<false><<<gg, 256, 0, stream>>>(vb, Wvt, nullptr, Vp, M_TOT, D_MODEL, D_MODEL);
  dim3 fg(N_ / 64, NHEAD, B_);
  kfrag_k<<<fg, 256, 0, stream>>>(Kp, Kf);
  vfrag_k<<<fg, 256, 0, stream>>>(Vp, Vf);
  attn_fwd<<<512, 256, 0, stream>>>(Qp, Kf, Vf, Mb, attn_out);
  gemm_bt<true><<<gg, 256, 0, stream>>>(attn_out, Wot, out, nullptr, M_TOT, D_MODEL, D_MODEL);
}

// Round 16
// 260.937 us; speedup vs baseline: 1.3046x; 1.1002x over previous
//
#include <hip/hip_runtime.h>
#include <hip/hip_bf16.h>

typedef unsigned short u16;
typedef unsigned int u32;
typedef short s16x8 __attribute__((ext_vector_type(8)));
typedef float f32x4 __attribute__((ext_vector_type(4)));
typedef float f32x16 __attribute__((ext_vector_type(16)));
typedef u16 u16x4 __attribute__((ext_vector_type(4)));
typedef u32 u32x4 __attribute__((ext_vector_type(4)));

#define D_MODEL 1024
#define NHEAD 16
#define DK 64
#define B_ 4
#define N_ 2048
#define M_TOT (B_ * N_) /* 8192 */
#define QBLK 128
#define KVBLK 64
#define SCALE2 0.1803368801111137f /* 0.125 * log2(e) */
#define FRAG_PER_BH 131072 /* N_*DK elems per (b,h) */
#define EX2(x) __builtin_amdgcn_exp2f(x) /* raw v_exp_f32 */

__device__ __forceinline__ u16 f2b(float x) {
  __hip_bfloat16 h = __float2bfloat16(x);
  return __builtin_bit_cast(u16, h);
}

__device__ __forceinline__ u32 cvtpk(float lo, float hi) {
  u32 r;
  asm("v_cvt_pk_bf16_f32 %0, %1, %2" : "=v"(r) : "v"(lo), "v"(hi));
  return r;
}

__device__ __forceinline__ void gload_lds16(const void* gp, void* lp) {
  __builtin_amdgcn_global_load_lds(
      (const __attribute__((address_space(1))) unsigned int*)gp,
      (__attribute__((address_space(3))) unsigned int*)lp, 16, 0, 0);
}

// ---------------- fused elementwise f32 -> bf16 (q,k,v in one launch) -----
__global__ __launch_bounds__(256) void cvt3_f32_bf16(const float* __restrict__ x0,
                                                     const float* __restrict__ x1,
                                                     const float* __restrict__ x2,
                                                     u16* __restrict__ y0,
                                                     u16* __restrict__ y1,
                                                     u16* __restrict__ y2, int n4) {
  int z = blockIdx.y;
  const float* x = z == 0 ? x0 : (z == 1 ? x1 : x2);
  u16* y = z == 0 ? y0 : (z == 1 ? y1 : y2);
  int i = blockIdx.x * 256 + threadIdx.x;
  if (i < n4) {
    f32x4 v = *(const f32x4*)(x + (size_t)i * 4);
    u16x4 o;
    o[0] = f2b(v[0]); o[1] = f2b(v[1]); o[2] = f2b(v[2]); o[3] = f2b(v[3]);
    *(u16x4*)(y + (size_t)i * 4) = o;
  }
}

// ---------------- padding mask -> float bias (0 or -inf) ----------------
__global__ __launch_bounds__(256) void mask_bias(const int* __restrict__ mask,
                                                 float* __restrict__ Mb, int n) {
  int i = blockIdx.x * 256 + threadIdx.x;
  if (i < n) Mb[i] = mask[i] ? 0.f : -INFINITY;
}

// ------------- fused W transpose: 4 weights in one launch -------------
__global__ __launch_bounds__(256) void wtrans4(const float* __restrict__ W0,
                                               const float* __restrict__ W1,
                                               const float* __restrict__ W2,
                                               const float* __restrict__ W3,
                                               u16* __restrict__ T0,
                                               u16* __restrict__ T1,
                                               u16* __restrict__ T2,
                                               u16* __restrict__ T3) {
  __shared__ float tile[32][33];
  int z = blockIdx.z;
  const float* W = z == 0 ? W0 : (z == 1 ? W1 : (z == 2 ? W2 : W3));
  u16* Wt = z == 0 ? T0 : (z == 1 ? T1 : (z == 2 ? T2 : T3));
  int bi = blockIdx.y, bj = blockIdx.x;
  int tx = threadIdx.x & 31, ty = threadIdx.x >> 5; // 32 x 8
#pragma unroll
  for (int r = 0; r < 4; ++r)
    tile[ty + r * 8][tx] = W[(size_t)(bi * 32 + ty + r * 8) * D_MODEL + bj * 32 + tx];
  __syncthreads();
#pragma unroll
  for (int r = 0; r < 4; ++r)
    Wt[(size_t)(bj * 32 + ty + r * 8) * D_MODEL + bi * 32 + tx] = f2b(tile[tx][ty + r * 8]);
}

// ------------- K [B,N,H*64] -> fragment-major Kf -------------
__global__ __launch_bounds__(256) void kfrag_k(const u16* __restrict__ Kp,
                                               u16* __restrict__ Kf) {
  __shared__ __align__(16) u16 tile[64][72];
  int kv0 = blockIdx.x * 64, h = blockIdx.y, b = blockIdx.z;
  int tid = threadIdx.x;
#pragma unroll
  for (int it = 0; it < 2; ++it) {
    int r = it * 32 + (tid >> 3), c8 = (tid & 7) * 8;
    *(s16x8*)&tile[r][c8] =
        *(const s16x8*)&Kp[(size_t)(b * N_ + kv0 + r) * D_MODEL + h * DK + c8];
  }
  __syncthreads();
  int w = tid >> 6, lane = tid & 63;
  int q32 = lane & 31, hi = lane >> 5;
  size_t kfb = (size_t)(b * NHEAD + h) * FRAG_PER_BH;
#pragma unroll
  for (int kv32L = 0; kv32L < 2; ++kv32L) {
    s16x8 v = *(const s16x8*)&tile[kv32L * 32 + q32][w * 16 + hi * 8];
    *(s16x8*)&Kf[kfb + ((size_t)(kv0 / 32 + kv32L) * 4 + w) * 512 + lane * 8] = v;
  }
}

// ------------- V [B,N,H*64] -> fragment-major Vf -------------
__global__ __launch_bounds__(256) void vfrag_k(const u16* __restrict__ Vp,
                                               u16* __restrict__ Vf) {
  __shared__ __align__(16) u16 tile[64][72];
  int n0 = blockIdx.x * 64, h = blockIdx.y, b = blockIdx.z;
  int tid = threadIdx.x;
#pragma unroll
  for (int it = 0; it < 2; ++it) {
    int r = it * 32 + (tid >> 3), c8 = (tid & 7) * 8;
    *(s16x8*)&tile[r][c8] =
        *(const s16x8*)&Vp[(size_t)(b * N_ + n0 + r) * D_MODEL + h * DK + c8];
  }
  __syncthreads();
  int w = tid >> 6, lane = tid & 63; // w = local kv16 index
  int d32 = lane & 31, hi = lane >> 5;
  size_t vfb = (size_t)(b * NHEAD + h) * FRAG_PER_BH;
#pragma unroll
  for (int d0 = 0; d0 < 2; ++d0) {
    s16x8 vv;
#pragma unroll
    for (int e = 0; e < 8; ++e)
      vv[e] = (short)tile[w * 16 + hi * 8 + e][d0 * 32 + d32];
    *(s16x8*)&Vf[vfb + ((size_t)(n0 / 16 + w) * 2 + d0) * 512 + lane * 8] = vv;
  }
}

// ------------- GEMM body: C[8192,1024] = A * Bt^T, XCD-local bi-rows ------
// Flat 512-block grid. xcd = bid&7 owns bi in [xcd*8, xcd*8+8), all bj:
// per-XCD working set = A-panel (2MB) + B (2MB) = 4MB = its L2.
template <bool OUT_F32>
__device__ __forceinline__ void gemm_body(const u16* __restrict__ A,
                                          const u16* __restrict__ Bt,
                                          float* __restrict__ Cf,
                                          u16* __restrict__ Cb) {
  const int M = M_TOT, N = D_MODEL, K = D_MODEL;
  __shared__ __align__(16) u16 Atile[128 * 32];
  __shared__ __align__(16) u16 Btile[128 * 32];
  int tid = threadIdx.x;
  int w = tid >> 6, lane = tid & 63;
  int g = lane >> 4, c = lane & 15;
  int wr = w >> 1, wc = w & 1;
  int bid = blockIdx.x;
  int xcd = bid & 7, idx = bid >> 3;
  int bi = xcd * 8 + (idx & 7);
  int bj = idx >> 3;
  const int rowA0 = bi * 128, rowB0 = bj * 128;

  const f32x4 fzero = {0.f, 0.f, 0.f, 0.f};
  f32x4 acc[4][4];
#pragma unroll
  for (int m = 0; m < 4; ++m)
#pragma unroll
    for (int n = 0; n < 4; ++n) acc[m][n] = fzero;

  for (int k0 = 0; k0 < K; k0 += 32) {
#pragma unroll
    for (int cc = 0; cc < 2; ++cc) {
      int li = w * 2 + cc;
      const u16* ga = A + (size_t)(rowA0 + li * 16 + (lane >> 2)) * K + k0 + (lane & 3) * 8;
      gload_lds16(ga, &Atile[li * 512]);
      const u16* gb = Bt + (size_t)(rowB0 + li * 16 + (lane >> 2)) * K + k0 + (lane & 3) * 8;
      gload_lds16(gb, &Btile[li * 512]);
    }
    __syncthreads();
    s16x8 af[4], bfr[4];
#pragma unroll
    for (int m = 0; m < 4; ++m)
      af[m] = *(const s16x8*)&Atile[(wr * 64 + m * 16 + c) * 32 + g * 8];
#pragma unroll
    for (int n = 0; n < 4; ++n)
      bfr[n] = *(const s16x8*)&Btile[(wc * 64 + n * 16 + c) * 32 + g * 8];
#pragma unroll
    for (int m = 0; m < 4; ++m)
#pragma unroll
      for (int n = 0; n < 4; ++n)
        acc[m][n] = __builtin_amdgcn_mfma_f32_16x16x32_bf16(af[m], bfr[n], acc[m][n], 0, 0, 0);
    __syncthreads();
  }
#pragma unroll
  for (int m = 0; m < 4; ++m)
#pragma unroll
    for (int n = 0; n < 4; ++n)
#pragma unroll
      for (int r = 0; r < 4; ++r) {
        int row = rowA0 + wr * 64 + m * 16 + g * 4 + r;
        int col = rowB0 + wc * 64 + n * 16 + c;
        size_t idxo = (size_t)row * N + col;
        if (OUT_F32) Cf[idxo] = acc[m][n][r];
        else Cb[idxo] = f2b(acc[m][n][r]);
      }
}

__global__ __launch_bounds__(256) void gemm_b16(const u16* __restrict__ A,
                                                const u16* __restrict__ Bt,
                                                u16* __restrict__ C) {
  gemm_body<false>(A, Bt, nullptr, C);
}

__global__ __launch_bounds__(256) void gemm_f32(const u16* __restrict__ A,
                                                const u16* __restrict__ Bt,
                                                float* __restrict__ C) {
  gemm_body<true>(A, Bt, C, nullptr);
}

#define MAX4(a, b, c, d) fmaxf(fmaxf(a, b), fmaxf(c, d))

// ------------- causal flash attention: 32x32 MFMA, fragment-major K/V -----
// R15 best: paired q-tiles {15-p,p}, XCD-local heads, zero LDS, no barriers,
// in-register softmax (cvt_pk+permlane32_swap), defer-max, K reg dbuf
// prefetch, pointer-bump addressing, raw v_exp_f32.
__global__ __launch_bounds__(256) void attn_fwd(const u16* __restrict__ Qp,
                                                const u16* __restrict__ Kf,
                                                const u16* __restrict__ Vf,
                                                const float* __restrict__ Mb,
                                                u16* __restrict__ Out) {
  int bid = blockIdx.x;
  int xcd = bid & 7;
  int inner = bid >> 3; // 0..63
  int j = inner >> 3;   // head-within-XCD 0..7
  int pair = inner & 7; // 0..7
  int bh = xcd * 8 + j; // 0..63
  int b = bh >> 4, h = bh & 15;
  int tid = threadIdx.x, w = tid >> 6, lane = tid & 63;
  int q32 = lane & 31, hi = lane >> 5;
  int hi8 = hi * 8, hi4 = hi * 4;

  const u16* kfb0 = Kf + (size_t)(b * NHEAD + h) * FRAG_PER_BH + lane * 8;
  const u16* vfb0 = Vf + (size_t)(b * NHEAD + h) * FRAG_PER_BH + lane * 8;
  const float* mb0 = Mb + (size_t)b * N_ + hi4;

  const f32x16 fz16 = {0.f, 0.f, 0.f, 0.f, 0.f, 0.f, 0.f, 0.f,
                       0.f, 0.f, 0.f, 0.f, 0.f, 0.f, 0.f, 0.f};

#pragma unroll 1
  for (int ph = 0; ph < 2; ++ph) {
    int qt = ph ? pair : 15 - pair;
    int q0 = qt * QBLK;
    int wq0 = q0 + w * 32; // this wave's first q row
    int ntw = wq0 / KVBLK + 1;
    int qq = wq0 + q32;

    const u16* kfp = kfb0;
    const u16* vfp = vfb0;
    const float* mpl = mb0;

    // Q (B-operand): lane holds Q[wq0+q32][kk*16+hi*8+e]
    s16x8 qf[4];
    {
      const u16* qb2 = Qp + (size_t)(b * N_ + wq0 + q32) * D_MODEL + h * DK;
#pragma unroll
      for (int kk = 0; kk < 4; ++kk) qf[kk] = *(const s16x8*)(qb2 + kk * 16 + hi8);
    }

    f32x16 oacc[2];
    oacc[0] = fz16; oacc[1] = fz16;
    float mr = -1e30f, lr = 0.f; // per-lane (q=q32); lr = half-row partial

    auto loadk = [&](s16x8(&kf)[2][4], const u16* kp) {
#pragma unroll
      for (int n = 0; n < 2; ++n)
#pragma unroll
        for (int kk = 0; kk < 4; ++kk)
          kf[n][kk] = *(const s16x8*)(kp + (n * 4 + kk) * 512);
    };

    auto step = [&](s16x8(&kc)[2][4], s16x8(&kn)[2][4], int t) {
      int kv0 = t * KVBLK;
      if (t + 1 < ntw) loadk(kn, kfp + 4096); // prefetch next tile
      s16x8 vf[2][2][2];
#pragma unroll
      for (int n = 0; n < 2; ++n)
#pragma unroll
        for (int kk2 = 0; kk2 < 2; ++kk2)
#pragma unroll
          for (int d0 = 0; d0 < 2; ++d0)
            vf[n][kk2][d0] = *(const s16x8*)(vfp + ((n * 2 + kk2) * 2 + d0) * 512);
      f32x4 mbv[2][4];
#pragma unroll
      for (int n = 0; n < 2; ++n)
#pragma unroll
        for (int jj = 0; jj < 4; ++jj)
          mbv[n][jj] = *(const f32x4*)(mpl + n * 32 + jj * 8);

      // ---- S^T = K Q^T
      f32x16 st[2];
#pragma unroll
      for (int n = 0; n < 2; ++n) {
        f32x16 a = fz16;
        a = __builtin_amdgcn_mfma_f32_32x32x16_bf16(kc[n][0], qf[0], a, 0, 0, 0);
        a = __builtin_amdgcn_mfma_f32_32x32x16_bf16(kc[n][1], qf[1], a, 0, 0, 0);
        a = __builtin_amdgcn_mfma_f32_32x32x16_bf16(kc[n][2], qf[2], a, 0, 0, 0);
        a = __builtin_amdgcn_mfma_f32_32x32x16_bf16(kc[n][3], qf[3], a, 0, 0, 0);
        st[n] = a;
      }

      // ---- scale + padding bias + causal mask
      bool diag = (kv0 + KVBLK - 1 > wq0);
#pragma unroll
      for (int n = 0; n < 2; ++n)
#pragma unroll
        for (int r = 0; r < 16; ++r) {
          float v = fmaf(st[n][r], SCALE2, mbv[n][r >> 2][r & 3]);
          if (diag) {
            int kv = kv0 + n * 32 + (r & 3) + 8 * (r >> 2) + hi4;
            v = (kv > qq) ? -INFINITY : v;
          }
          st[n][r] = v;
        }
      float a0 = MAX4(st[0][0], st[0][1], st[0][2], st[0][3]);
      float a1 = MAX4(st[0][4], st[0][5], st[0][6], st[0][7]);
      float a2 = MAX4(st[0][8], st[0][9], st[0][10], st[0][11]);
      float a3 = MAX4(st[0][12], st[0][13], st[0][14], st[0][15]);
      float b0 = MAX4(st[1][0], st[1][1], st[1][2], st[1][3]);
      float b1 = MAX4(st[1][4], st[1][5], st[1][6], st[1][7]);
      float b2 = MAX4(st[1][8], st[1][9], st[1][10], st[1][11]);
      float b3 = MAX4(st[1][12], st[1][13], st[1][14], st[1][15]);
      float pmax = fmaxf(MAX4(a0, a1, a2, a3), MAX4(b0, b1, b2, b3));

      // ---- defer-max rescale (T13)
      if (__any(pmax > mr + 8.f)) {
        float pm2 = fmaxf(pmax, __shfl_xor(pmax, 32));
        float mnew = fmaxf(mr, pm2);
        float al = EX2(mr - mnew);
        mr = mnew;
        lr *= al;
#pragma unroll
        for (int r = 0; r < 16; ++r) {
          float alT = __shfl(al, (r & 3) + 8 * (r >> 2) + hi4);
          oacc[0][r] *= alT;
          oacc[1][r] *= alT;
        }
      }

      // ---- p = exp2(s - m) (raw v_exp_f32), pack -> PV A-frags (T12)
      s16x8 pa[2][2];
#pragma unroll
      for (int n = 0; n < 2; ++n) {
#pragma unroll
        for (int r = 0; r < 16; ++r) st[n][r] = EX2(st[n][r] - mr);
        float s01 = st[n][0] + st[n][1], s23 = st[n][2] + st[n][3];
        float s45 = st[n][4] + st[n][5], s67 = st[n][6] + st[n][7];
        float s89 = st[n][8] + st[n][9], sab = st[n][10] + st[n][11];
        float scd = st[n][12] + st[n][13], sef = st[n][14] + st[n][15];
        lr += ((s01 + s23) + (s45 + s67)) + ((s89 + sab) + (scd + sef));
        u32 x0 = cvtpk(st[n][0], st[n][1]);
        u32 x1 = cvtpk(st[n][2], st[n][3]);
        u32 x2 = cvtpk(st[n][4], st[n][5]);
        u32 x3 = cvtpk(st[n][6], st[n][7]);
        auto sA = __builtin_amdgcn_permlane32_swap(x0, x2, false, false);
        auto sB = __builtin_amdgcn_permlane32_swap(x1, x3, false, false);
        u32x4 w0 = {sA[0], sB[0], sA[1], sB[1]};
        pa[n][0] = __builtin_bit_cast(s16x8, w0);
        u32 x4 = cvtpk(st[n][8], st[n][9]);
        u32 x5 = cvtpk(st[n][10], st[n][11]);
        u32 x6 = cvtpk(st[n][12], st[n][13]);
        u32 x7 = cvtpk(st[n][14], st[n][15]);
        auto sC = __builtin_amdgcn_permlane32_swap(x4, x6, false, false);
        auto sD = __builtin_amdgcn_permlane32_swap(x5, x7, false, false);
        u32x4 w1 = {sC[0], sD[0], sC[1], sD[1]};
        pa[n][1] = __builtin_bit_cast(s16x8, w1);
      }

      // ---- O += P * V (in-register A-operand)
#pragma unroll
      for (int n = 0; n < 2; ++n)
#pragma unroll
        for (int kk2 = 0; kk2 < 2; ++kk2)
#pragma unroll
          for (int d0 = 0; d0 < 2; ++d0)
            oacc[d0] = __builtin_amdgcn_mfma_f32_32x32x16_bf16(pa[n][kk2], vf[n][kk2][d0], oacc[d0], 0, 0, 0);

      kfp += 4096;
      vfp += 4096;
      mpl += KVBLK;
    };

    s16x8 kA[2][4], kB[2][4];
    loadk(kA, kfp);
    for (int t = 0; t < ntw; t += 2) {
      step(kA, kB, t);
      if (t + 1 < ntw) step(kB, kA, t + 1);
    }

    // ---- epilogue: complete l across lane pair, normalize + store
    lr += __shfl_xor(lr, 32);
#pragma unroll
    for (int r = 0; r < 16; ++r) {
      int qoff = (r & 3) + 8 * (r >> 2) + hi4;
      float lq = __shfl(lr, qoff);
      float inv = lq > 0.f ? 1.f / lq : 0.f;
      size_t base = (size_t)(b * N_ + wq0 + qoff) * D_MODEL + h * DK + q32;
      Out[base] = f2b(oacc[0][r] * inv);
      Out[base + 32] = f2b(oacc[1][r] * inv);
    }
  }
}

extern "C" void kernel_launch(void* const* d_in, const int* in_sizes, int n_in,
                              void* d_out, int out_size, void* d_ws, size_t ws_size,
                              hipStream_t stream) {
  const float* q = (const float*)d_in[0];
  const float* k = (const float*)d_in[1];
  const float* v = (const float*)d_in[2];
  const int* mask = (const int*)d_in[3];
  const float* Wq = (const float*)d_in[4];
  const float* Wk = (const float*)d_in[5];
  const float* Wv = (const float*)d_in[6];
  const float* Wo = (const float*)d_in[7];
  float* out = (float*)d_out;

  char* ws = (char*)d_ws;
  const size_t SZ = (size_t)M_TOT * D_MODEL * 2; // 16 MiB per bf16 [8192,1024]
  u16* qb = (u16*)ws;            // cvt(q) -> Q GEMM; then Vp; then attn_out
  u16* kb = (u16*)(ws + SZ);     // cvt(k) -> K GEMM; then Kf
  u16* vb = (u16*)(ws + 2 * SZ); // cvt(v) -> V GEMM; then Vf
  u16* Qp = (u16*)(ws + 3 * SZ);
  u16* Kp = (u16*)(ws + 4 * SZ);
  u16* Wqt = (u16*)(ws + 5 * SZ);
  u16* Wkt = Wqt + 1024 * 1024;
  u16* Wvt = Wkt + 1024 * 1024;
  u16* Wot = Wvt + 1024 * 1024;
  float* Mb = (float*)(Wot + 1024 * 1024);
  // lifetime-disjoint aliases:
  u16* Vp = qb;       // qb dead after Q GEMM; Vp dead after vfrag
  u16* Kf = kb;       // kb dead after K GEMM
  u16* Vf = vb;       // vb dead after V GEMM
  u16* attn_out = qb; // Vp dead after vfrag

  int n4 = M_TOT * D_MODEL / 4;
  cvt3_f32_bf16<<<dim3(n4 / 256, 3), 256, 0, stream>>>(q, k, v, qb, kb, vb, n4);
  mask_bias<<<(B_ * N_ + 255) / 256, 256, 0, stream>>>(mask, Mb, B_ * N_);
  wtrans4<<<dim3(32, 32, 4), 256, 0, stream>>>(Wq, Wk, Wv, Wo, Wqt, Wkt, Wvt, Wot);
  gemm_b16<<<512, 256, 0, stream>>>(qb, Wqt, Qp);
  gemm_b16<<<512, 256, 0, stream>>>(kb, Wkt, Kp);
  gemm_b16<<<512, 256, 0, stream>>>(vb, Wvt, Vp);
  dim3 fg(N_ / 64, NHEAD, B_);
  kfrag_k<<<fg, 256, 0, stream>>>(Kp, Kf);
  vfrag_k<<<fg, 256, 0, stream>>>(Vp, Vf);
  attn_fwd<<<512, 256, 0, stream>>>(Qp, Kf, Vf, Mb, attn_out);
  gemm_f32<<<512, 256, 0, stream>>>(attn_out, Wot, out);
}

// Round 17
// 245.063 us; speedup vs baseline: 1.3891x; 1.0648x over previous
//
#include <hip/hip_runtime.h>
#include <hip/hip_bf16.h>

typedef unsigned short u16;
typedef unsigned int u32;
typedef short s16x8 __attribute__((ext_vector_type(8)));
typedef float f32x4 __attribute__((ext_vector_type(4)));
typedef float f32x16 __attribute__((ext_vector_type(16)));
typedef u16 u16x4 __attribute__((ext_vector_type(4)));
typedef u32 u32x4 __attribute__((ext_vector_type(4)));

#define D_MODEL 1024
#define NHEAD 16
#define DK 64
#define B_ 4
#define N_ 2048
#define M_TOT (B_ * N_) /* 8192 */
#define QBLK 128
#define KVBLK 64
#define SCALE2 0.1803368801111137f /* 0.125 * log2(e) */
#define FRAG_PER_BH 131072 /* N_*DK elems per (b,h) */
#define EX2(x) __builtin_amdgcn_exp2f(x) /* raw v_exp_f32 */

__device__ __forceinline__ u16 f2b(float x) {
  __hip_bfloat16 h = __float2bfloat16(x);
  return __builtin_bit_cast(u16, h);
}

__device__ __forceinline__ u32 cvtpk(float lo, float hi) {
  u32 r;
  asm("v_cvt_pk_bf16_f32 %0, %1, %2" : "=v"(r) : "v"(lo), "v"(hi));
  return r;
}

__device__ __forceinline__ void gload_lds16(const void* gp, void* lp) {
  __builtin_amdgcn_global_load_lds(
      (const __attribute__((address_space(1))) unsigned int*)gp,
      (__attribute__((address_space(3))) unsigned int*)lp, 16, 0, 0);
}

// ---------------- fused elementwise f32 -> bf16 (q,k,v in one launch) -----
__global__ __launch_bounds__(256) void cvt3_f32_bf16(const float* __restrict__ x0,
                                                     const float* __restrict__ x1,
                                                     const float* __restrict__ x2,
                                                     u16* __restrict__ y0,
                                                     u16* __restrict__ y1,
                                                     u16* __restrict__ y2, int n4) {
  int z = blockIdx.y;
  const float* x = z == 0 ? x0 : (z == 1 ? x1 : x2);
  u16* y = z == 0 ? y0 : (z == 1 ? y1 : y2);
  int i = blockIdx.x * 256 + threadIdx.x;
  if (i < n4) {
    f32x4 v = *(const f32x4*)(x + (size_t)i * 4);
    u16x4 o;
    o[0] = f2b(v[0]); o[1] = f2b(v[1]); o[2] = f2b(v[2]); o[3] = f2b(v[3]);
    *(u16x4*)(y + (size_t)i * 4) = o;
  }
}

// ---------------- padding mask -> float bias (0 or -inf) ----------------
__global__ __launch_bounds__(256) void mask_bias(const int* __restrict__ mask,
                                                 float* __restrict__ Mb, int n) {
  int i = blockIdx.x * 256 + threadIdx.x;
  if (i < n) Mb[i] = mask[i] ? 0.f : -INFINITY;
}

// ------------- fused W transpose: 4 weights in one launch -------------
__global__ __launch_bounds__(256) void wtrans4(const float* __restrict__ W0,
                                               const float* __restrict__ W1,
                                               const float* __restrict__ W2,
                                               const float* __restrict__ W3,
                                               u16* __restrict__ T0,
                                               u16* __restrict__ T1,
                                               u16* __restrict__ T2,
                                               u16* __restrict__ T3) {
  __shared__ float tile[32][33];
  int z = blockIdx.z;
  const float* W = z == 0 ? W0 : (z == 1 ? W1 : (z == 2 ? W2 : W3));
  u16* Wt = z == 0 ? T0 : (z == 1 ? T1 : (z == 2 ? T2 : T3));
  int bi = blockIdx.y, bj = blockIdx.x;
  int tx = threadIdx.x & 31, ty = threadIdx.x >> 5; // 32 x 8
#pragma unroll
  for (int r = 0; r < 4; ++r)
    tile[ty + r * 8][tx] = W[(size_t)(bi * 32 + ty + r * 8) * D_MODEL + bj * 32 + tx];
  __syncthreads();
#pragma unroll
  for (int r = 0; r < 4; ++r)
    Wt[(size_t)(bj * 32 + ty + r * 8) * D_MODEL + bi * 32 + tx] = f2b(tile[tx][ty + r * 8]);
}

// ------------- GEMM body: C = A[8192,1024] * Bt[1024,1024]^T --------------
// XCD-local bi-rows (per-XCD WS = A-panel 2MB + B 2MB = L2).
// MODE 0: f32 row-major; MODE 1: bf16 fragment-major (K/Q layout);
// MODE 2: bf16 fragment-major (V layout).
template <int MODE>
__device__ __forceinline__ void gemm_body(const u16* __restrict__ A,
                                          const u16* __restrict__ Bt,
                                          float* __restrict__ Cf,
                                          u16* __restrict__ Cb) {
  const int N = D_MODEL, K = D_MODEL;
  __shared__ __align__(16) u16 Atile[128 * 32];
  __shared__ __align__(16) u16 Btile[128 * 32];
  int tid = threadIdx.x;
  int w = tid >> 6, lane = tid & 63;
  int g = lane >> 4, c = lane & 15;
  int wr = w >> 1, wc = w & 1;
  int bid = blockIdx.x;
  int xcd = bid & 7, idx = bid >> 3;
  int bi = xcd * 8 + (idx & 7);
  int bj = idx >> 3;
  const int rowA0 = bi * 128, rowB0 = bj * 128;

  const f32x4 fzero = {0.f, 0.f, 0.f, 0.f};
  f32x4 acc[4][4];
#pragma unroll
  for (int m = 0; m < 4; ++m)
#pragma unroll
    for (int n = 0; n < 4; ++n) acc[m][n] = fzero;

  for (int k0 = 0; k0 < K; k0 += 32) {
#pragma unroll
    for (int cc = 0; cc < 2; ++cc) {
      int li = w * 2 + cc;
      const u16* ga = A + (size_t)(rowA0 + li * 16 + (lane >> 2)) * K + k0 + (lane & 3) * 8;
      gload_lds16(ga, &Atile[li * 512]);
      const u16* gb = Bt + (size_t)(rowB0 + li * 16 + (lane >> 2)) * K + k0 + (lane & 3) * 8;
      gload_lds16(gb, &Btile[li * 512]);
    }
    __syncthreads();
    s16x8 af[4], bfr[4];
#pragma unroll
    for (int m = 0; m < 4; ++m)
      af[m] = *(const s16x8*)&Atile[(wr * 64 + m * 16 + c) * 32 + g * 8];
#pragma unroll
    for (int n = 0; n < 4; ++n)
      bfr[n] = *(const s16x8*)&Btile[(wc * 64 + n * 16 + c) * 32 + g * 8];
#pragma unroll
    for (int m = 0; m < 4; ++m)
#pragma unroll
      for (int n = 0; n < 4; ++n)
        acc[m][n] = __builtin_amdgcn_mfma_f32_16x16x32_bf16(af[m], bfr[n], acc[m][n], 0, 0, 0);
    __syncthreads();
  }

  if (MODE == 0) {
#pragma unroll
    for (int m = 0; m < 4; ++m)
#pragma unroll
      for (int n = 0; n < 4; ++n)
#pragma unroll
        for (int r = 0; r < 4; ++r) {
          int row = rowA0 + wr * 64 + m * 16 + g * 4 + r;
          int col = rowB0 + wc * 64 + n * 16 + c;
          Cf[(size_t)row * N + col] = acc[m][n][r];
        }
  } else if (MODE == 1) {
    // K/Q fragment layout: lane l holds X[f32*32+(l&31)][kk*16+(l>>5)*8+e]
    int bb = rowA0 >> 11;
    int hloc = bj * 2 + wc;
    size_t fb = ((size_t)bb * NHEAD + hloc) * FRAG_PER_BH;
#pragma unroll
    for (int m = 0; m < 4; ++m) {
      int rowm = rowA0 + wr * 64 + m * 16;
      size_t f32b = (size_t)((rowm & 2047) >> 5) * 4;
      int lpart = (m & 1) * 16 + g * 4 + (c >> 3) * 32;
#pragma unroll
      for (int n = 0; n < 4; ++n)
#pragma unroll
        for (int r = 0; r < 4; ++r)
          Cb[fb + (f32b + n) * 512 + (size_t)(lpart + r) * 8 + (c & 7)] = f2b(acc[m][n][r]);
    }
  } else {
    // V fragment layout: lane l holds V[kv16*16+(l>>5)*8+e][d0*32+(l&31)]
    int bb = rowA0 >> 11;
    int hloc = bj * 2 + wc;
    size_t fb = ((size_t)bb * NHEAD + hloc) * FRAG_PER_BH;
#pragma unroll
    for (int m = 0; m < 4; ++m) {
      int rowm = rowA0 + wr * 64 + m * 16; // +g*4+r < 16
      size_t kv16b = (size_t)((rowm & 2047) >> 4) * 2;
#pragma unroll
      for (int n = 0; n < 4; ++n) {
        size_t idxo = fb + (kv16b + (n >> 1)) * 512 +
                      (size_t)((n & 1) * 16 + c + (g >> 1) * 32) * 8 + (g & 1) * 4;
        u16x4 pv;
        pv[0] = f2b(acc[m][n][0]); pv[1] = f2b(acc[m][n][1]);
        pv[2] = f2b(acc[m][n][2]); pv[3] = f2b(acc[m][n][3]);
        *(u16x4*)&Cb[idxo] = pv;
      }
    }
  }
}

__global__ __launch_bounds__(256) void gemm_kfrag(const u16* __restrict__ A,
                                                  const u16* __restrict__ Bt,
                                                  u16* __restrict__ C) {
  gemm_body<1>(A, Bt, nullptr, C);
}

__global__ __launch_bounds__(256) void gemm_vfrag(const u16* __restrict__ A,
                                                  const u16* __restrict__ Bt,
                                                  u16* __restrict__ C) {
  gemm_body<2>(A, Bt, nullptr, C);
}

__global__ __launch_bounds__(256) void gemm_f32(const u16* __restrict__ A,
                                                const u16* __restrict__ Bt,
                                                float* __restrict__ C) {
  gemm_body<0>(A, Bt, C, nullptr);
}

#define MAX4(a, b, c, d) fmaxf(fmaxf(a, b), fmaxf(c, d))

// ------------- causal flash attention: 32x32 MFMA, fragment-major Q/K/V ---
// R15 best + (a) VMEM issue order V,mask first / K-prefetch LAST so the
// mask-phase wait is vmcnt(8), keeping prefetch in flight across the step;
// (b) Q loaded from fragment-major (coalesced).
__global__ __launch_bounds__(256) void attn_fwd(const u16* __restrict__ Qf,
                                                const u16* __restrict__ Kf,
                                                const u16* __restrict__ Vf,
                                                const float* __restrict__ Mb,
                                                u16* __restrict__ Out) {
  int bid = blockIdx.x;
  int xcd = bid & 7;
  int inner = bid >> 3; // 0..63
  int j = inner >> 3;   // head-within-XCD 0..7
  int pair = inner & 7; // 0..7
  int bh = xcd * 8 + j; // 0..63
  int b = bh >> 4, h = bh & 15;
  int tid = threadIdx.x, w = tid >> 6, lane = tid & 63;
  int q32 = lane & 31, hi = lane >> 5;
  int hi4 = hi * 4;

  const u16* qfb0 = Qf + (size_t)(b * NHEAD + h) * FRAG_PER_BH + lane * 8;
  const u16* kfb0 = Kf + (size_t)(b * NHEAD + h) * FRAG_PER_BH + lane * 8;
  const u16* vfb0 = Vf + (size_t)(b * NHEAD + h) * FRAG_PER_BH + lane * 8;
  const float* mb0 = Mb + (size_t)b * N_ + hi4;

  const f32x16 fz16 = {0.f, 0.f, 0.f, 0.f, 0.f, 0.f, 0.f, 0.f,
                       0.f, 0.f, 0.f, 0.f, 0.f, 0.f, 0.f, 0.f};

#pragma unroll 1
  for (int ph = 0; ph < 2; ++ph) {
    int qt = ph ? pair : 15 - pair;
    int q0 = qt * QBLK;
    int wq0 = q0 + w * 32; // this wave's first q row
    int ntw = wq0 / KVBLK + 1;
    int qq = wq0 + q32;

    const u16* kfp = kfb0;
    const u16* vfp = vfb0;
    const float* mpl = mb0;

    // Q (B-operand) from fragment-major: frag group wq0/32, kk 0..3
    s16x8 qf[4];
#pragma unroll
    for (int kk = 0; kk < 4; ++kk)
      qf[kk] = *(const s16x8*)(qfb0 + ((size_t)((wq0 >> 5) * 4 + kk)) * 512);

    f32x16 oacc[2];
    oacc[0] = fz16; oacc[1] = fz16;
    float mr = -1e30f, lr = 0.f;

    auto loadk = [&](s16x8(&kf)[2][4], const u16* kp) {
#pragma unroll
      for (int n = 0; n < 2; ++n)
#pragma unroll
        for (int kk = 0; kk < 4; ++kk)
          kf[n][kk] = *(const s16x8*)(kp + (n * 4 + kk) * 512);
    };

    auto step = [&](s16x8(&kc)[2][4], s16x8(&kn)[2][4], int t) {
      int kv0 = t * KVBLK;
      // V + mask FIRST...
      s16x8 vf[2][2][2];
#pragma unroll
      for (int n = 0; n < 2; ++n)
#pragma unroll
        for (int kk2 = 0; kk2 < 2; ++kk2)
#pragma unroll
          for (int d0 = 0; d0 < 2; ++d0)
            vf[n][kk2][d0] = *(const s16x8*)(vfp + ((n * 2 + kk2) * 2 + d0) * 512);
      f32x4 mbv[2][4];
#pragma unroll
      for (int n = 0; n < 2; ++n)
#pragma unroll
        for (int jj = 0; jj < 4; ++jj)
          mbv[n][jj] = *(const f32x4*)(mpl + n * 32 + jj * 8);
      // ...K-prefetch LAST (stays in flight across the step: vmcnt(8) waits)
      if (t + 1 < ntw) loadk(kn, kfp + 4096);

      // ---- S^T = K Q^T
      f32x16 st[2];
#pragma unroll
      for (int n = 0; n < 2; ++n) {
        f32x16 a = fz16;
        a = __builtin_amdgcn_mfma_f32_32x32x16_bf16(kc[n][0], qf[0], a, 0, 0, 0);
        a = __builtin_amdgcn_mfma_f32_32x32x16_bf16(kc[n][1], qf[1], a, 0, 0, 0);
        a = __builtin_amdgcn_mfma_f32_32x32x16_bf16(kc[n][2], qf[2], a, 0, 0, 0);
        a = __builtin_amdgcn_mfma_f32_32x32x16_bf16(kc[n][3], qf[3], a, 0, 0, 0);
        st[n] = a;
      }

      // ---- scale + padding bias + causal mask
      bool diag = (kv0 + KVBLK - 1 > wq0);
#pragma unroll
      for (int n = 0; n < 2; ++n)
#pragma unroll
        for (int r = 0; r < 16; ++r) {
          float v = fmaf(st[n][r], SCALE2, mbv[n][r >> 2][r & 3]);
          if (diag) {
            int kv = kv0 + n * 32 + (r & 3) + 8 * (r >> 2) + hi4;
            v = (kv > qq) ? -INFINITY : v;
          }
          st[n][r] = v;
        }
      float a0 = MAX4(st[0][0], st[0][1], st[0][2], st[0][3]);
      float a1 = MAX4(st[0][4], st[0][5], st[0][6], st[0][7]);
      float a2 = MAX4(st[0][8], st[0][9], st[0][10], st[0][11]);
      float a3 = MAX4(st[0][12], st[0][13], st[0][14], st[0][15]);
      float b0 = MAX4(st[1][0], st[1][1], st[1][2], st[1][3]);
      float b1 = MAX4(st[1][4], st[1][5], st[1][6], st[1][7]);
      float b2 = MAX4(st[1][8], st[1][9], st[1][10], st[1][11]);
      float b3 = MAX4(st[1][12], st[1][13], st[1][14], st[1][15]);
      float pmax = fmaxf(MAX4(a0, a1, a2, a3), MAX4(b0, b1, b2, b3));

      // ---- defer-max rescale (T13)
      if (__any(pmax > mr + 8.f)) {
        float pm2 = fmaxf(pmax, __shfl_xor(pmax, 32));
        float mnew = fmaxf(mr, pm2);
        float al = EX2(mr - mnew);
        mr = mnew;
        lr *= al;
#pragma unroll
        for (int r = 0; r < 16; ++r) {
          float alT = __shfl(al, (r & 3) + 8 * (r >> 2) + hi4);
          oacc[0][r] *= alT;
          oacc[1][r] *= alT;
        }
      }

      // ---- p = exp2(s - m), pack -> PV A-frags (T12)
      s16x8 pa[2][2];
#pragma unroll
      for (int n = 0; n < 2; ++n) {
#pragma unroll
        for (int r = 0; r < 16; ++r) st[n][r] = EX2(st[n][r] - mr);
        float s01 = st[n][0] + st[n][1], s23 = st[n][2] + st[n][3];
        float s45 = st[n][4] + st[n][5], s67 = st[n][6] + st[n][7];
        float s89 = st[n][8] + st[n][9], sab = st[n][10] + st[n][11];
        float scd = st[n][12] + st[n][13], sef = st[n][14] + st[n][15];
        lr += ((s01 + s23) + (s45 + s67)) + ((s89 + sab) + (scd + sef));
        u32 x0 = cvtpk(st[n][0], st[n][1]);
        u32 x1 = cvtpk(st[n][2], st[n][3]);
        u32 x2 = cvtpk(st[n][4], st[n][5]);
        u32 x3 = cvtpk(st[n][6], st[n][7]);
        auto sA = __builtin_amdgcn_permlane32_swap(x0, x2, false, false);
        auto sB = __builtin_amdgcn_permlane32_swap(x1, x3, false, false);
        u32x4 w0 = {sA[0], sB[0], sA[1], sB[1]};
        pa[n][0] = __builtin_bit_cast(s16x8, w0);
        u32 x4 = cvtpk(st[n][8], st[n][9]);
        u32 x5 = cvtpk(st[n][10], st[n][11]);
        u32 x6 = cvtpk(st[n][12], st[n][13]);
        u32 x7 = cvtpk(st[n][14], st[n][15]);
        auto sC = __builtin_amdgcn_permlane32_swap(x4, x6, false, false);
        auto sD = __builtin_amdgcn_permlane32_swap(x5, x7, false, false);
        u32x4 w1 = {sC[0], sD[0], sC[1], sD[1]};
        pa[n][1] = __builtin_bit_cast(s16x8, w1);
      }

      // ---- O += P * V (in-register A-operand)
#pragma unroll
      for (int n = 0; n < 2; ++n)
#pragma unroll
        for (int kk2 = 0; kk2 < 2; ++kk2)
#pragma unroll
          for (int d0 = 0; d0 < 2; ++d0)
            oacc[d0] = __builtin_amdgcn_mfma_f32_32x32x16_bf16(pa[n][kk2], vf[n][kk2][d0], oacc[d0], 0, 0, 0);

      kfp += 4096;
      vfp += 4096;
      mpl += KVBLK;
    };

    s16x8 kA[2][4], kB[2][4];
    loadk(kA, kfp);
    for (int t = 0; t < ntw; t += 2) {
      step(kA, kB, t);
      if (t + 1 < ntw) step(kB, kA, t + 1);
    }

    // ---- epilogue: complete l across lane pair, normalize + store
    lr += __shfl_xor(lr, 32);
#pragma unroll
    for (int r = 0; r < 16; ++r) {
      int qoff = (r & 3) + 8 * (r >> 2) + hi4;
      float lq = __shfl(lr, qoff);
      float inv = lq > 0.f ? 1.f / lq : 0.f;
      size_t base = (size_t)(b * N_ + wq0 + qoff) * D_MODEL + h * DK + q32;
      Out[base] = f2b(oacc[0][r] * inv);
      Out[base + 32] = f2b(oacc[1][r] * inv);
    }
  }
}

extern "C" void kernel_launch(void* const* d_in, const int* in_sizes, int n_in,
                              void* d_out, int out_size, void* d_ws, size_t ws_size,
                              hipStream_t stream) {
  const float* q = (const float*)d_in[0];
  const float* k = (const float*)d_in[1];
  const float* v = (const float*)d_in[2];
  const int* mask = (const int*)d_in[3];
  const float* Wq = (const float*)d_in[4];
  const float* Wk = (const float*)d_in[5];
  const float* Wv = (const float*)d_in[6];
  const float* Wo = (const float*)d_in[7];
  float* out = (float*)d_out;

  char* ws = (char*)d_ws;
  const size_t SZ = (size_t)M_TOT * D_MODEL * 2; // 16 MiB per bf16 [8192,1024]
  u16* qb = (u16*)ws;            // cvt(q); dead after Q GEMM
  u16* kb = (u16*)(ws + SZ);     // cvt(k); dead after K GEMM
  u16* vb = (u16*)(ws + 2 * SZ); // cvt(v); dead after V GEMM
  u16* Qf = (u16*)(ws + 3 * SZ);
  u16* Vf = (u16*)(ws + 4 * SZ);
  u16* Wqt = (u16*)(ws + 5 * SZ);
  u16* Wkt = Wqt + 1024 * 1024;
  u16* Wvt = Wkt + 1024 * 1024;
  u16* Wot = Wvt + 1024 * 1024;
  float* Mb = (float*)(Wot + 1024 * 1024);
  // lifetime-disjoint aliases:
  u16* Kf = qb;       // qb dead after Q GEMM; K GEMM writes Kf here
  u16* attn_out = kb; // kb dead after K GEMM; attn writes here

  int n4 = M_TOT * D_MODEL / 4;
  cvt3_f32_bf16<<<dim3(n4 / 256, 3), 256, 0, stream>>>(q, k, v, qb, kb, vb, n4);
  mask_bias<<<(B_ * N_ + 255) / 256, 256, 0, stream>>>(mask, Mb, B_ * N_);
  wtrans4<<<dim3(32, 32, 4), 256, 0, stream>>>(Wq, Wk, Wv, Wo, Wqt, Wkt, Wvt, Wot);
  gemm_kfrag<<<512, 256, 0, stream>>>(qb, Wqt, Qf); // Q -> frag-major
  gemm_kfrag<<<512, 256, 0, stream>>>(kb, Wkt, Kf); // K -> frag-major (into old qb)
  gemm_vfrag<<<512, 256, 0, stream>>>(vb, Wvt, Vf); // V -> frag-major
  attn_fwd<<<512, 256, 0, stream>>>(Qf, Kf, Vf, Mb, attn_out);
  gemm_f32<<<512, 256, 0, stream>>>(attn_out, Wot, out);
}

// Round 18
// 226.902 us; speedup vs baseline: 1.5003x; 1.0800x over previous
//
#include <hip/hip_runtime.h>
#include <hip/hip_bf16.h>

typedef unsigned short u16;
typedef unsigned int u32;
typedef short s16x8 __attribute__((ext_vector_type(8)));
typedef float f32x4 __attribute__((ext_vector_type(4)));
typedef float f32x16 __attribute__((ext_vector_type(16)));
typedef u16 u16x4 __attribute__((ext_vector_type(4)));
typedef u32 u32x4 __attribute__((ext_vector_type(4)));

#define D_MODEL 1024
#define NHEAD 16
#define DK 64
#define B_ 4
#define N_ 2048
#define M_TOT (B_ * N_) /* 8192 */
#define QBLK 128
#define KVBLK 64
#define SCALE2 0.1803368801111137f /* 0.125 * log2(e) */
#define FRAG_PER_BH 131072 /* N_*DK elems per (b,h) */
#define EX2(x) __builtin_amdgcn_exp2f(x) /* raw v_exp_f32 */

__device__ __forceinline__ u16 f2b(float x) {
  __hip_bfloat16 h = __float2bfloat16(x);
  return __builtin_bit_cast(u16, h);
}

__device__ __forceinline__ u32 cvtpk(float lo, float hi) {
  u32 r;
  asm("v_cvt_pk_bf16_f32 %0, %1, %2" : "=v"(r) : "v"(lo), "v"(hi));
  return r;
}

__device__ __forceinline__ void gload_lds16(const void* gp, void* lp) {
  __builtin_amdgcn_global_load_lds(
      (const __attribute__((address_space(1))) unsigned int*)gp,
      (__attribute__((address_space(3))) unsigned int*)lp, 16, 0, 0);
}

// ---------------- fused elementwise f32 -> bf16 (q,k,v in one launch) -----
__global__ __launch_bounds__(256) void cvt3_f32_bf16(const float* __restrict__ x0,
                                                     const float* __restrict__ x1,
                                                     const float* __restrict__ x2,
                                                     u16* __restrict__ y0,
                                                     u16* __restrict__ y1,
                                                     u16* __restrict__ y2, int n4) {
  int z = blockIdx.y;
  const float* x = z == 0 ? x0 : (z == 1 ? x1 : x2);
  u16* y = z == 0 ? y0 : (z == 1 ? y1 : y2);
  int i = blockIdx.x * 256 + threadIdx.x;
  if (i < n4) {
    f32x4 v = *(const f32x4*)(x + (size_t)i * 4);
    u16x4 o;
    o[0] = f2b(v[0]); o[1] = f2b(v[1]); o[2] = f2b(v[2]); o[3] = f2b(v[3]);
    *(u16x4*)(y + (size_t)i * 4) = o;
  }
}

// ---------------- padding mask -> float bias (0 or -inf) ----------------
__global__ __launch_bounds__(256) void mask_bias(const int* __restrict__ mask,
                                                 float* __restrict__ Mb, int n) {
  int i = blockIdx.x * 256 + threadIdx.x;
  if (i < n) Mb[i] = mask[i] ? 0.f : -INFINITY;
}

// ------------- fused W transpose: 4 weights in one launch -------------
__global__ __launch_bounds__(256) void wtrans4(const float* __restrict__ W0,
                                               const float* __restrict__ W1,
                                               const float* __restrict__ W2,
                                               const float* __restrict__ W3,
                                               u16* __restrict__ T0,
                                               u16* __restrict__ T1,
                                               u16* __restrict__ T2,
                                               u16* __restrict__ T3) {
  __shared__ float tile[32][33];
  int z = blockIdx.z;
  const float* W = z == 0 ? W0 : (z == 1 ? W1 : (z == 2 ? W2 : W3));
  u16* Wt = z == 0 ? T0 : (z == 1 ? T1 : (z == 2 ? T2 : T3));
  int bi = blockIdx.y, bj = blockIdx.x;
  int tx = threadIdx.x & 31, ty = threadIdx.x >> 5; // 32 x 8
#pragma unroll
  for (int r = 0; r < 4; ++r)
    tile[ty + r * 8][tx] = W[(size_t)(bi * 32 + ty + r * 8) * D_MODEL + bj * 32 + tx];
  __syncthreads();
#pragma unroll
  for (int r = 0; r < 4; ++r)
    Wt[(size_t)(bj * 32 + ty + r * 8) * D_MODEL + bi * 32 + tx] = f2b(tile[tx][ty + r * 8]);
}

// ------------- GEMM body: C = A[8192,1024] * Bt[1024,1024]^T --------------
// XCD-local bi-rows (per-XCD WS = A-panel 2MB + B 2MB = L2).
// MODE 0: f32 row-major; MODE 1: bf16 fragment-major (K/Q layout);
// MODE 2: bf16 fragment-major (V layout).
template <int MODE>
__device__ __forceinline__ void gemm_body(const u16* __restrict__ A,
                                          const u16* __restrict__ Bt,
                                          float* __restrict__ Cf,
                                          u16* __restrict__ Cb) {
  const int N = D_MODEL, K = D_MODEL;
  __shared__ __align__(16) u16 Atile[128 * 32];
  __shared__ __align__(16) u16 Btile[128 * 32];
  int tid = threadIdx.x;
  int w = tid >> 6, lane = tid & 63;
  int g = lane >> 4, c = lane & 15;
  int wr = w >> 1, wc = w & 1;
  int bid = blockIdx.x;
  int xcd = bid & 7, idx = bid >> 3;
  int bi = xcd * 8 + (idx & 7);
  int bj = idx >> 3;
  const int rowA0 = bi * 128, rowB0 = bj * 128;

  const f32x4 fzero = {0.f, 0.f, 0.f, 0.f};
  f32x4 acc[4][4];
#pragma unroll
  for (int m = 0; m < 4; ++m)
#pragma unroll
    for (int n = 0; n < 4; ++n) acc[m][n] = fzero;

  for (int k0 = 0; k0 < K; k0 += 32) {
#pragma unroll
    for (int cc = 0; cc < 2; ++cc) {
      int li = w * 2 + cc;
      const u16* ga = A + (size_t)(rowA0 + li * 16 + (lane >> 2)) * K + k0 + (lane & 3) * 8;
      gload_lds16(ga, &Atile[li * 512]);
      const u16* gb = Bt + (size_t)(rowB0 + li * 16 + (lane >> 2)) * K + k0 + (lane & 3) * 8;
      gload_lds16(gb, &Btile[li * 512]);
    }
    __syncthreads();
    s16x8 af[4], bfr[4];
#pragma unroll
    for (int m = 0; m < 4; ++m)
      af[m] = *(const s16x8*)&Atile[(wr * 64 + m * 16 + c) * 32 + g * 8];
#pragma unroll
    for (int n = 0; n < 4; ++n)
      bfr[n] = *(const s16x8*)&Btile[(wc * 64 + n * 16 + c) * 32 + g * 8];
#pragma unroll
    for (int m = 0; m < 4; ++m)
#pragma unroll
      for (int n = 0; n < 4; ++n)
        acc[m][n] = __builtin_amdgcn_mfma_f32_16x16x32_bf16(af[m], bfr[n], acc[m][n], 0, 0, 0);
    __syncthreads();
  }

  if (MODE == 0) {
#pragma unroll
    for (int m = 0; m < 4; ++m)
#pragma unroll
      for (int n = 0; n < 4; ++n)
#pragma unroll
        for (int r = 0; r < 4; ++r) {
          int row = rowA0 + wr * 64 + m * 16 + g * 4 + r;
          int col = rowB0 + wc * 64 + n * 16 + c;
          Cf[(size_t)row * N + col] = acc[m][n][r];
        }
  } else if (MODE == 1) {
    // K/Q fragment layout: lane l holds X[f32*32+(l&31)][kk*16+(l>>5)*8+e]
    int bb = rowA0 >> 11;
    int hloc = bj * 2 + wc;
    size_t fb = ((size_t)bb * NHEAD + hloc) * FRAG_PER_BH;
#pragma unroll
    for (int m = 0; m < 4; ++m) {
      int rowm = rowA0 + wr * 64 + m * 16;
      size_t f32b = (size_t)((rowm & 2047) >> 5) * 4;
      int lpart = (m & 1) * 16 + g * 4 + (c >> 3) * 32;
#pragma unroll
      for (int n = 0; n < 4; ++n)
#pragma unroll
        for (int r = 0; r < 4; ++r)
          Cb[fb + (f32b + n) * 512 + (size_t)(lpart + r) * 8 + (c & 7)] = f2b(acc[m][n][r]);
    }
  } else {
    // V fragment layout: lane l holds V[kv16*16+(l>>5)*8+e][d0*32+(l&31)]
    int bb = rowA0 >> 11;
    int hloc = bj * 2 + wc;
    size_t fb = ((size_t)bb * NHEAD + hloc) * FRAG_PER_BH;
#pragma unroll
    for (int m = 0; m < 4; ++m) {
      int rowm = rowA0 + wr * 64 + m * 16; // +g*4+r < 16
      size_t kv16b = (size_t)((rowm & 2047) >> 4) * 2;
#pragma unroll
      for (int n = 0; n < 4; ++n) {
        size_t idxo = fb + (kv16b + (n >> 1)) * 512 +
                      (size_t)((n & 1) * 16 + c + (g >> 1) * 32) * 8 + (g & 1) * 4;
        u16x4 pv;
        pv[0] = f2b(acc[m][n][0]); pv[1] = f2b(acc[m][n][1]);
        pv[2] = f2b(acc[m][n][2]); pv[3] = f2b(acc[m][n][3]);
        *(u16x4*)&Cb[idxo] = pv;
      }
    }
  }
}

// fused Q/K/V projection: blockIdx.y picks operand set + epilogue layout
__global__ __launch_bounds__(256) void gemm_qkv(const u16* __restrict__ Aq,
                                                const u16* __restrict__ Ak,
                                                const u16* __restrict__ Av,
                                                const u16* __restrict__ Btq,
                                                const u16* __restrict__ Btk,
                                                const u16* __restrict__ Btv,
                                                u16* __restrict__ Cq,
                                                u16* __restrict__ Ck,
                                                u16* __restrict__ Cv) {
  int z = blockIdx.y;
  if (z == 0) gemm_body<1>(Aq, Btq, nullptr, Cq);
  else if (z == 1) gemm_body<1>(Ak, Btk, nullptr, Ck);
  else gemm_body<2>(Av, Btv, nullptr, Cv);
}

__global__ __launch_bounds__(256) void gemm_f32(const u16* __restrict__ A,
                                                const u16* __restrict__ Bt,
                                                float* __restrict__ C) {
  gemm_body<0>(A, Bt, C, nullptr);
}

#define MAX4(a, b, c, d) fmaxf(fmaxf(a, b), fmaxf(c, d))

// ------------- causal flash attention: 32x32 MFMA, fragment-major Q/K/V ---
// One WAVE per block (64 threads): zero LDS + zero barriers means block size
// is semantically free; 1-wave blocks let HW pack 3 waves/SIMD (504<=512
// VGPR) and backfill at wave granularity. 2048 blocks = 64 bh x 8 pairs x
// 4 wave-slots; paired q-tiles {15-p, p} keep per-block work uniform.
__global__ __launch_bounds__(64) void attn_fwd(const u16* __restrict__ Qf,
                                               const u16* __restrict__ Kf,
                                               const u16* __restrict__ Vf,
                                               const float* __restrict__ Mb,
                                               u16* __restrict__ Out) {
  int bid = blockIdx.x;
  int xcd = bid & 7;
  int inner = bid >> 3;  // 0..255
  int j = inner >> 5;    // head-within-XCD 0..7
  int u = inner & 31;    // 0..31
  int pair = u >> 2;     // 0..7
  int w = u & 3;         // wave-slot 0..3
  int bh = xcd * 8 + j;  // 0..63
  int b = bh >> 4, h = bh & 15;
  int lane = threadIdx.x & 63;
  int q32 = lane & 31, hi = lane >> 5;
  int hi4 = hi * 4;

  const u16* qfb0 = Qf + (size_t)(b * NHEAD + h) * FRAG_PER_BH + lane * 8;
  const u16* kfb0 = Kf + (size_t)(b * NHEAD + h) * FRAG_PER_BH + lane * 8;
  const u16* vfb0 = Vf + (size_t)(b * NHEAD + h) * FRAG_PER_BH + lane * 8;
  const float* mb0 = Mb + (size_t)b * N_ + hi4;

  const f32x16 fz16 = {0.f, 0.f, 0.f, 0.f, 0.f, 0.f, 0.f, 0.f,
                       0.f, 0.f, 0.f, 0.f, 0.f, 0.f, 0.f, 0.f};

#pragma unroll 1
  for (int ph = 0; ph < 2; ++ph) {
    int qt = ph ? pair : 15 - pair;
    int q0 = qt * QBLK;
    int wq0 = q0 + w * 32; // this wave's first q row
    int ntw = wq0 / KVBLK + 1;
    int qq = wq0 + q32;

    const u16* kfp = kfb0;
    const u16* vfp = vfb0;
    const float* mpl = mb0;

    // Q (B-operand) from fragment-major: frag group wq0/32, kk 0..3
    s16x8 qf[4];
#pragma unroll
    for (int kk = 0; kk < 4; ++kk)
      qf[kk] = *(const s16x8*)(qfb0 + ((size_t)((wq0 >> 5) * 4 + kk)) * 512);

    f32x16 oacc[2];
    oacc[0] = fz16; oacc[1] = fz16;
    float mr = -1e30f, lr = 0.f;

    auto loadk = [&](s16x8(&kf)[2][4], const u16* kp) {
#pragma unroll
      for (int n = 0; n < 2; ++n)
#pragma unroll
        for (int kk = 0; kk < 4; ++kk)
          kf[n][kk] = *(const s16x8*)(kp + (n * 4 + kk) * 512);
    };

    auto step = [&](s16x8(&kc)[2][4], s16x8(&kn)[2][4], int t) {
      int kv0 = t * KVBLK;
      // V + mask FIRST...
      s16x8 vf[2][2][2];
#pragma unroll
      for (int n = 0; n < 2; ++n)
#pragma unroll
        for (int kk2 = 0; kk2 < 2; ++kk2)
#pragma unroll
          for (int d0 = 0; d0 < 2; ++d0)
            vf[n][kk2][d0] = *(const s16x8*)(vfp + ((n * 2 + kk2) * 2 + d0) * 512);
      f32x4 mbv[2][4];
#pragma unroll
      for (int n = 0; n < 2; ++n)
#pragma unroll
        for (int jj = 0; jj < 4; ++jj)
          mbv[n][jj] = *(const f32x4*)(mpl + n * 32 + jj * 8);
      // ...K-prefetch LAST (stays in flight across the step)
      if (t + 1 < ntw) loadk(kn, kfp + 4096);

      // ---- S^T = K Q^T
      f32x16 st[2];
#pragma unroll
      for (int n = 0; n < 2; ++n) {
        f32x16 a = fz16;
        a = __builtin_amdgcn_mfma_f32_32x32x16_bf16(kc[n][0], qf[0], a, 0, 0, 0);
        a = __builtin_amdgcn_mfma_f32_32x32x16_bf16(kc[n][1], qf[1], a, 0, 0, 0);
        a = __builtin_amdgcn_mfma_f32_32x32x16_bf16(kc[n][2], qf[2], a, 0, 0, 0);
        a = __builtin_amdgcn_mfma_f32_32x32x16_bf16(kc[n][3], qf[3], a, 0, 0, 0);
        st[n] = a;
      }

      // ---- scale + padding bias + causal mask
      bool diag = (kv0 + KVBLK - 1 > wq0);
#pragma unroll
      for (int n = 0; n < 2; ++n)
#pragma unroll
        for (int r = 0; r < 16; ++r) {
          float v = fmaf(st[n][r], SCALE2, mbv[n][r >> 2][r & 3]);
          if (diag) {
            int kv = kv0 + n * 32 + (r & 3) + 8 * (r >> 2) + hi4;
            v = (kv > qq) ? -INFINITY : v;
          }
          st[n][r] = v;
        }
      float a0 = MAX4(st[0][0], st[0][1], st[0][2], st[0][3]);
      float a1 = MAX4(st[0][4], st[0][5], st[0][6], st[0][7]);
      float a2 = MAX4(st[0][8], st[0][9], st[0][10], st[0][11]);
      float a3 = MAX4(st[0][12], st[0][13], st[0][14], st[0][15]);
      float b0 = MAX4(st[1][0], st[1][1], st[1][2], st[1][3]);
      float b1 = MAX4(st[1][4], st[1][5], st[1][6], st[1][7]);
      float b2 = MAX4(st[1][8], st[1][9], st[1][10], st[1][11]);
      float b3 = MAX4(st[1][12], st[1][13], st[1][14], st[1][15]);
      float pmax = fmaxf(MAX4(a0, a1, a2, a3), MAX4(b0, b1, b2, b3));

      // ---- defer-max rescale (T13)
      if (__any(pmax > mr + 8.f)) {
        float pm2 = fmaxf(pmax, __shfl_xor(pmax, 32));
        float mnew = fmaxf(mr, pm2);
        float al = EX2(mr - mnew);
        mr = mnew;
        lr *= al;
#pragma unroll
        for (int r = 0; r < 16; ++r) {
          float alT = __shfl(al, (r & 3) + 8 * (r >> 2) + hi4);
          oacc[0][r] *= alT;
          oacc[1][r] *= alT;
        }
      }

      // ---- p = exp2(s - m), pack -> PV A-frags (T12)
      s16x8 pa[2][2];
#pragma unroll
      for (int n = 0; n < 2; ++n) {
#pragma unroll
        for (int r = 0; r < 16; ++r) st[n][r] = EX2(st[n][r] - mr);
        float s01 = st[n][0] + st[n][1], s23 = st[n][2] + st[n][3];
        float s45 = st[n][4] + st[n][5], s67 = st[n][6] + st[n][7];
        float s89 = st[n][8] + st[n][9], sab = st[n][10] + st[n][11];
        float scd = st[n][12] + st[n][13], sef = st[n][14] + st[n][15];
        lr += ((s01 + s23) + (s45 + s67)) + ((s89 + sab) + (scd + sef));
        u32 x0 = cvtpk(st[n][0], st[n][1]);
        u32 x1 = cvtpk(st[n][2], st[n][3]);
        u32 x2 = cvtpk(st[n][4], st[n][5]);
        u32 x3 = cvtpk(st[n][6], st[n][7]);
        auto sA = __builtin_amdgcn_permlane32_swap(x0, x2, false, false);
        auto sB = __builtin_amdgcn_permlane32_swap(x1, x3, false, false);
        u32x4 w0 = {sA[0], sB[0], sA[1], sB[1]};
        pa[n][0] = __builtin_bit_cast(s16x8, w0);
        u32 x4 = cvtpk(st[n][8], st[n][9]);
        u32 x5 = cvtpk(st[n][10], st[n][11]);
        u32 x6 = cvtpk(st[n][12], st[n][13]);
        u32 x7 = cvtpk(st[n][14], st[n][15]);
        auto sC = __builtin_amdgcn_permlane32_swap(x4, x6, false, false);
        auto sD = __builtin_amdgcn_permlane32_swap(x5, x7, false, false);
        u32x4 w1 = {sC[0], sD[0], sC[1], sD[1]};
        pa[n][1] = __builtin_bit_cast(s16x8, w1);
      }

      // ---- O += P * V (in-register A-operand)
#pragma unroll
      for (int n = 0; n < 2; ++n)
#pragma unroll
        for (int kk2 = 0; kk2 < 2; ++kk2)
#pragma unroll
          for (int d0 = 0; d0 < 2; ++d0)
            oacc[d0] = __builtin_amdgcn_mfma_f32_32x32x16_bf16(pa[n][kk2], vf[n][kk2][d0], oacc[d0], 0, 0, 0);

      kfp += 4096;
      vfp += 4096;
      mpl += KVBLK;
    };

    s16x8 kA[2][4], kB[2][4];
    loadk(kA, kfp);
    for (int t = 0; t < ntw; t += 2) {
      step(kA, kB, t);
      if (t + 1 < ntw) step(kB, kA, t + 1);
    }

    // ---- epilogue: complete l across lane pair, normalize + store
    lr += __shfl_xor(lr, 32);
#pragma unroll
    for (int r = 0; r < 16; ++r) {
      int qoff = (r & 3) + 8 * (r >> 2) + hi4;
      float lq = __shfl(lr, qoff);
      float inv = lq > 0.f ? 1.f / lq : 0.f;
      size_t base = (size_t)(b * N_ + wq0 + qoff) * D_MODEL + h * DK + q32;
      Out[base] = f2b(oacc[0][r] * inv);
      Out[base + 32] = f2b(oacc[1][r] * inv);
    }
  }
}

extern "C" void kernel_launch(void* const* d_in, const int* in_sizes, int n_in,
                              void* d_out, int out_size, void* d_ws, size_t ws_size,
                              hipStream_t stream) {
  const float* q = (const float*)d_in[0];
  const float* k = (const float*)d_in[1];
  const float* v = (const float*)d_in[2];
  const int* mask = (const int*)d_in[3];
  const float* Wq = (const float*)d_in[4];
  const float* Wk = (const float*)d_in[5];
  const float* Wv = (const float*)d_in[6];
  const float* Wo = (const float*)d_in[7];
  float* out = (float*)d_out;

  char* ws = (char*)d_ws;
  const size_t SZ = (size_t)M_TOT * D_MODEL * 2; // 16 MiB per bf16 [8192,1024]
  u16* qb = (u16*)ws;            // cvt(q); dead after Q GEMM
  u16* kb = (u16*)(ws + SZ);     // cvt(k); dead after K GEMM
  u16* vb = (u16*)(ws + 2 * SZ); // cvt(v); dead after V GEMM
  u16* Qf = (u16*)(ws + 3 * SZ);
  u16* Vf = (u16*)(ws + 4 * SZ);
  u16* Wqt = (u16*)(ws + 5 * SZ);
  u16* Wkt = Wqt + 1024 * 1024;
  u16* Wvt = Wkt + 1024 * 1024;
  u16* Wot = Wvt + 1024 * 1024;
  float* Mb = (float*)(Wot + 1024 * 1024);
  // lifetime-disjoint aliases:
  u16* Kf = qb;       // qb dead after Q GEMM (z=0 reads qb, z=1 writes Kf..
                      // ..same buffer! -> K output must NOT alias qb in the
                      // fused launch; use dedicated region instead:
  Kf = (u16*)(ws + 5 * SZ + 4 * 2 * 1024 * 1024 + ((B_ * N_ * 4 + 255) & ~255));
  u16* attn_out = kb; // kb dead after K GEMM; attn writes here

  int n4 = M_TOT * D_MODEL / 4;
  cvt3_f32_bf16<<<dim3(n4 / 256, 3), 256, 0, stream>>>(q, k, v, qb, kb, vb, n4);
  mask_bias<<<(B_ * N_ + 255) / 256, 256, 0, stream>>>(mask, Mb, B_ * N_);
  wtrans4<<<dim3(32, 32, 4), 256, 0, stream>>>(Wq, Wk, Wv, Wo, Wqt, Wkt, Wvt, Wot);
  gemm_qkv<<<dim3(512, 3), 256, 0, stream>>>(qb, kb, vb, Wqt, Wkt, Wvt, Qf, Kf, Vf);
  attn_fwd<<<2048, 64, 0, stream>>>(Qf, Kf, Vf, Mb, attn_out);
  gemm_f32<<<512, 256, 0, stream>>>(attn_out, Wot, out);
}

// Round 19
// 224.534 us; speedup vs baseline: 1.5161x; 1.0105x over previous
//
#include <hip/hip_runtime.h>
#include <hip/hip_bf16.h>

typedef unsigned short u16;
typedef unsigned int u32;
typedef short s16x8 __attribute__((ext_vector_type(8)));
typedef float f32x4 __attribute__((ext_vector_type(4)));
typedef float f32x16 __attribute__((ext_vector_type(16)));
typedef u16 u16x4 __attribute__((ext_vector_type(4)));
typedef u32 u32x4 __attribute__((ext_vector_type(4)));

#define D_MODEL 1024
#define NHEAD 16
#define DK 64
#define B_ 4
#define N_ 2048
#define M_TOT (B_ * N_) /* 8192 */
#define QBLK 128
#define KVBLK 64
#define SCALE2 0.1803368801111137f /* 0.125 * log2(e) */
#define FRAG_PER_BH 131072 /* N_*DK elems per (b,h) */
#define EX2(x) __builtin_amdgcn_exp2f(x) /* raw v_exp_f32 */

__device__ __forceinline__ u16 f2b(float x) {
  __hip_bfloat16 h = __float2bfloat16(x);
  return __builtin_bit_cast(u16, h);
}

__device__ __forceinline__ u32 cvtpk(float lo, float hi) {
  u32 r;
  asm("v_cvt_pk_bf16_f32 %0, %1, %2" : "=v"(r) : "v"(lo), "v"(hi));
  return r;
}

__device__ __forceinline__ void gload_lds16(const void* gp, void* lp) {
  __builtin_amdgcn_global_load_lds(
      (const __attribute__((address_space(1))) unsigned int*)gp,
      (__attribute__((address_space(3))) unsigned int*)lp, 16, 0, 0);
}

// ---------------- fused elementwise f32 -> bf16 (q,k,v in one launch) -----
__global__ __launch_bounds__(256) void cvt3_f32_bf16(const float* __restrict__ x0,
                                                     const float* __restrict__ x1,
                                                     const float* __restrict__ x2,
                                                     u16* __restrict__ y0,
                                                     u16* __restrict__ y1,
                                                     u16* __restrict__ y2, int n4) {
  int z = blockIdx.y;
  const float* x = z == 0 ? x0 : (z == 1 ? x1 : x2);
  u16* y = z == 0 ? y0 : (z == 1 ? y1 : y2);
  int i = blockIdx.x * 256 + threadIdx.x;
  if (i < n4) {
    f32x4 v = *(const f32x4*)(x + (size_t)i * 4);
    u16x4 o;
    o[0] = f2b(v[0]); o[1] = f2b(v[1]); o[2] = f2b(v[2]); o[3] = f2b(v[3]);
    *(u16x4*)(y + (size_t)i * 4) = o;
  }
}

// ---------------- padding mask -> float bias (0 or -inf) ----------------
__global__ __launch_bounds__(256) void mask_bias(const int* __restrict__ mask,
                                                 float* __restrict__ Mb, int n) {
  int i = blockIdx.x * 256 + threadIdx.x;
  if (i < n) Mb[i] = mask[i] ? 0.f : -INFINITY;
}

// ------------- fused W transpose: 4 weights in one launch -------------
__global__ __launch_bounds__(256) void wtrans4(const float* __restrict__ W0,
                                               const float* __restrict__ W1,
                                               const float* __restrict__ W2,
                                               const float* __restrict__ W3,
                                               u16* __restrict__ T0,
                                               u16* __restrict__ T1,
                                               u16* __restrict__ T2,
                                               u16* __restrict__ T3) {
  __shared__ float tile[32][33];
  int z = blockIdx.z;
  const float* W = z == 0 ? W0 : (z == 1 ? W1 : (z == 2 ? W2 : W3));
  u16* Wt = z == 0 ? T0 : (z == 1 ? T1 : (z == 2 ? T2 : T3));
  int bi = blockIdx.y, bj = blockIdx.x;
  int tx = threadIdx.x & 31, ty = threadIdx.x >> 5; // 32 x 8
#pragma unroll
  for (int r = 0; r < 4; ++r)
    tile[ty + r * 8][tx] = W[(size_t)(bi * 32 + ty + r * 8) * D_MODEL + bj * 32 + tx];
  __syncthreads();
#pragma unroll
  for (int r = 0; r < 4; ++r)
    Wt[(size_t)(bj * 32 + ty + r * 8) * D_MODEL + bi * 32 + tx] = f2b(tile[tx][ty + r * 8]);
}

// ------------- GEMM body: C = A[8192,1024] * Bt[1024,1024]^T --------------
// XCD-local bi-rows (per-XCD WS = A-panel 2MB + B 2MB = L2).
// MODE 0: f32 row-major; MODE 1: bf16 fragment-major (K/Q layout);
// MODE 2: bf16 fragment-major (V layout).
template <int MODE>
__device__ __forceinline__ void gemm_body(const u16* __restrict__ A,
                                          const u16* __restrict__ Bt,
                                          float* __restrict__ Cf,
                                          u16* __restrict__ Cb) {
  const int N = D_MODEL, K = D_MODEL;
  __shared__ __align__(16) u16 Atile[128 * 32];
  __shared__ __align__(16) u16 Btile[128 * 32];
  int tid = threadIdx.x;
  int w = tid >> 6, lane = tid & 63;
  int g = lane >> 4, c = lane & 15;
  int wr = w >> 1, wc = w & 1;
  int bid = blockIdx.x;
  int xcd = bid & 7, idx = bid >> 3;
  int bi = xcd * 8 + (idx & 7);
  int bj = idx >> 3;
  const int rowA0 = bi * 128, rowB0 = bj * 128;

  const f32x4 fzero = {0.f, 0.f, 0.f, 0.f};
  f32x4 acc[4][4];
#pragma unroll
  for (int m = 0; m < 4; ++m)
#pragma unroll
    for (int n = 0; n < 4; ++n) acc[m][n] = fzero;

  for (int k0 = 0; k0 < K; k0 += 32) {
#pragma unroll
    for (int cc = 0; cc < 2; ++cc) {
      int li = w * 2 + cc;
      const u16* ga = A + (size_t)(rowA0 + li * 16 + (lane >> 2)) * K + k0 + (lane & 3) * 8;
      gload_lds16(ga, &Atile[li * 512]);
      const u16* gb = Bt + (size_t)(rowB0 + li * 16 + (lane >> 2)) * K + k0 + (lane & 3) * 8;
      gload_lds16(gb, &Btile[li * 512]);
    }
    __syncthreads();
    s16x8 af[4], bfr[4];
#pragma unroll
    for (int m = 0; m < 4; ++m)
      af[m] = *(const s16x8*)&Atile[(wr * 64 + m * 16 + c) * 32 + g * 8];
#pragma unroll
    for (int n = 0; n < 4; ++n)
      bfr[n] = *(const s16x8*)&Btile[(wc * 64 + n * 16 + c) * 32 + g * 8];
#pragma unroll
    for (int m = 0; m < 4; ++m)
#pragma unroll
      for (int n = 0; n < 4; ++n)
        acc[m][n] = __builtin_amdgcn_mfma_f32_16x16x32_bf16(af[m], bfr[n], acc[m][n], 0, 0, 0);
    __syncthreads();
  }

  if (MODE == 0) {
#pragma unroll
    for (int m = 0; m < 4; ++m)
#pragma unroll
      for (int n = 0; n < 4; ++n)
#pragma unroll
        for (int r = 0; r < 4; ++r) {
          int row = rowA0 + wr * 64 + m * 16 + g * 4 + r;
          int col = rowB0 + wc * 64 + n * 16 + c;
          Cf[(size_t)row * N + col] = acc[m][n][r];
        }
  } else if (MODE == 1) {
    // K/Q fragment layout: lane l holds X[f32*32+(l&31)][kk*16+(l>>5)*8+e]
    int bb = rowA0 >> 11;
    int hloc = bj * 2 + wc;
    size_t fb = ((size_t)bb * NHEAD + hloc) * FRAG_PER_BH;
#pragma unroll
    for (int m = 0; m < 4; ++m) {
      int rowm = rowA0 + wr * 64 + m * 16;
      size_t f32b = (size_t)((rowm & 2047) >> 5) * 4;
      int lpart = (m & 1) * 16 + g * 4 + (c >> 3) * 32;
#pragma unroll
      for (int n = 0; n < 4; ++n)
#pragma unroll
        for (int r = 0; r < 4; ++r)
          Cb[fb + (f32b + n) * 512 + (size_t)(lpart + r) * 8 + (c & 7)] = f2b(acc[m][n][r]);
    }
  } else {
    // V fragment layout: lane l holds V[kv16*16+(l>>5)*8+e][d0*32+(l&31)]
    int bb = rowA0 >> 11;
    int hloc = bj * 2 + wc;
    size_t fb = ((size_t)bb * NHEAD + hloc) * FRAG_PER_BH;
#pragma unroll
    for (int m = 0; m < 4; ++m) {
      int rowm = rowA0 + wr * 64 + m * 16; // +g*4+r < 16
      size_t kv16b = (size_t)((rowm & 2047) >> 4) * 2;
#pragma unroll
      for (int n = 0; n < 4; ++n) {
        size_t idxo = fb + (kv16b + (n >> 1)) * 512 +
                      (size_t)((n & 1) * 16 + c + (g >> 1) * 32) * 8 + (g & 1) * 4;
        u16x4 pv;
        pv[0] = f2b(acc[m][n][0]); pv[1] = f2b(acc[m][n][1]);
        pv[2] = f2b(acc[m][n][2]); pv[3] = f2b(acc[m][n][3]);
        *(u16x4*)&Cb[idxo] = pv;
      }
    }
  }
}

// fused Q/K/V projection: blockIdx.y picks operand set + epilogue layout
__global__ __launch_bounds__(256) void gemm_qkv(const u16* __restrict__ Aq,
                                                const u16* __restrict__ Ak,
                                                const u16* __restrict__ Av,
                                                const u16* __restrict__ Btq,
                                                const u16* __restrict__ Btk,
                                                const u16* __restrict__ Btv,
                                                u16* __restrict__ Cq,
                                                u16* __restrict__ Ck,
                                                u16* __restrict__ Cv) {
  int z = blockIdx.y;
  if (z == 0) gemm_body<1>(Aq, Btq, nullptr, Cq);
  else if (z == 1) gemm_body<1>(Ak, Btk, nullptr, Ck);
  else gemm_body<2>(Av, Btv, nullptr, Cv);
}

__global__ __launch_bounds__(256) void gemm_f32(const u16* __restrict__ A,
                                                const u16* __restrict__ Bt,
                                                float* __restrict__ C) {
  gemm_body<0>(A, Bt, C, nullptr);
}

#define MAX4(a, b, c, d) fmaxf(fmaxf(a, b), fmaxf(c, d))

// ------------- causal flash attention: 32x32 MFMA, fragment-major Q/K/V ---
// One WAVE per block; 4096 UNPAIRED blocks (bh, qt, w) heavy-first:
// supplies 16 waves/CU against the 12/CU VGPR ceiling -> 3 waves/SIMD
// resident with wave-granular backfill (fixes R18's 8-wave/CU supply cap).
__global__ __launch_bounds__(64) void attn_fwd(const u16* __restrict__ Qf,
                                               const u16* __restrict__ Kf,
                                               const u16* __restrict__ Vf,
                                               const float* __restrict__ Mb,
                                               u16* __restrict__ Out) {
  int bid = blockIdx.x;
  int xcd = bid & 7;
  int inner = bid >> 3;       // 0..511
  int j = inner >> 6;         // head-within-XCD 0..7
  int rem = inner & 63;       // 0..63
  int qt = 15 - (rem >> 2);   // heavy tiles first
  int w = rem & 3;            // wave-slot 0..3
  int bh = xcd * 8 + j;       // 0..63
  int b = bh >> 4, h = bh & 15;
  int lane = threadIdx.x & 63;
  int q32 = lane & 31, hi = lane >> 5;
  int hi4 = hi * 4;

  int q0 = qt * QBLK;
  int wq0 = q0 + w * 32; // this wave's first q row
  int ntw = wq0 / KVBLK + 1;
  int qq = wq0 + q32;

  const u16* qfb0 = Qf + (size_t)(b * NHEAD + h) * FRAG_PER_BH + lane * 8;
  const u16* kfp = Kf + (size_t)(b * NHEAD + h) * FRAG_PER_BH + lane * 8;
  const u16* vfp = Vf + (size_t)(b * NHEAD + h) * FRAG_PER_BH + lane * 8;
  const float* mpl = Mb + (size_t)b * N_ + hi4;

  const f32x16 fz16 = {0.f, 0.f, 0.f, 0.f, 0.f, 0.f, 0.f, 0.f,
                       0.f, 0.f, 0.f, 0.f, 0.f, 0.f, 0.f, 0.f};

  // Q (B-operand) from fragment-major: frag group wq0/32, kk 0..3
  s16x8 qf[4];
#pragma unroll
  for (int kk = 0; kk < 4; ++kk)
    qf[kk] = *(const s16x8*)(qfb0 + ((size_t)((wq0 >> 5) * 4 + kk)) * 512);

  f32x16 oacc[2];
  oacc[0] = fz16; oacc[1] = fz16;
  float mr = -1e30f, lr = 0.f;

  auto loadk = [&](s16x8(&kf)[2][4], const u16* kp) {
#pragma unroll
    for (int n = 0; n < 2; ++n)
#pragma unroll
      for (int kk = 0; kk < 4; ++kk)
        kf[n][kk] = *(const s16x8*)(kp + (n * 4 + kk) * 512);
  };

  auto step = [&](s16x8(&kc)[2][4], s16x8(&kn)[2][4], int t) {
    int kv0 = t * KVBLK;
    // V + mask FIRST...
    s16x8 vf[2][2][2];
#pragma unroll
    for (int n = 0; n < 2; ++n)
#pragma unroll
      for (int kk2 = 0; kk2 < 2; ++kk2)
#pragma unroll
        for (int d0 = 0; d0 < 2; ++d0)
          vf[n][kk2][d0] = *(const s16x8*)(vfp + ((n * 2 + kk2) * 2 + d0) * 512);
    f32x4 mbv[2][4];
#pragma unroll
    for (int n = 0; n < 2; ++n)
#pragma unroll
      for (int jj = 0; jj < 4; ++jj)
        mbv[n][jj] = *(const f32x4*)(mpl + n * 32 + jj * 8);
    // ...K-prefetch LAST (stays in flight across the step)
    if (t + 1 < ntw) loadk(kn, kfp + 4096);

    // ---- S^T = K Q^T
    f32x16 st[2];
#pragma unroll
    for (int n = 0; n < 2; ++n) {
      f32x16 a = fz16;
      a = __builtin_amdgcn_mfma_f32_32x32x16_bf16(kc[n][0], qf[0], a, 0, 0, 0);
      a = __builtin_amdgcn_mfma_f32_32x32x16_bf16(kc[n][1], qf[1], a, 0, 0, 0);
      a = __builtin_amdgcn_mfma_f32_32x32x16_bf16(kc[n][2], qf[2], a, 0, 0, 0);
      a = __builtin_amdgcn_mfma_f32_32x32x16_bf16(kc[n][3], qf[3], a, 0, 0, 0);
      st[n] = a;
    }

    // ---- scale + padding bias + causal mask
    bool diag = (kv0 + KVBLK - 1 > wq0);
#pragma unroll
    for (int n = 0; n < 2; ++n)
#pragma unroll
      for (int r = 0; r < 16; ++r) {
        float v = fmaf(st[n][r], SCALE2, mbv[n][r >> 2][r & 3]);
        if (diag) {
          int kv = kv0 + n * 32 + (r & 3) + 8 * (r >> 2) + hi4;
          v = (kv > qq) ? -INFINITY : v;
        }
        st[n][r] = v;
      }
    float a0 = MAX4(st[0][0], st[0][1], st[0][2], st[0][3]);
    float a1 = MAX4(st[0][4], st[0][5], st[0][6], st[0][7]);
    float a2 = MAX4(st[0][8], st[0][9], st[0][10], st[0][11]);
    float a3 = MAX4(st[0][12], st[0][13], st[0][14], st[0][15]);
    float b0 = MAX4(st[1][0], st[1][1], st[1][2], st[1][3]);
    float b1 = MAX4(st[1][4], st[1][5], st[1][6], st[1][7]);
    float b2 = MAX4(st[1][8], st[1][9], st[1][10], st[1][11]);
    float b3 = MAX4(st[1][12], st[1][13], st[1][14], st[1][15]);
    float pmax = fmaxf(MAX4(a0, a1, a2, a3), MAX4(b0, b1, b2, b3));

    // ---- defer-max rescale (T13)
    if (__any(pmax > mr + 8.f)) {
      float pm2 = fmaxf(pmax, __shfl_xor(pmax, 32));
      float mnew = fmaxf(mr, pm2);
      float al = EX2(mr - mnew);
      mr = mnew;
      lr *= al;
#pragma unroll
      for (int r = 0; r < 16; ++r) {
        float alT = __shfl(al, (r & 3) + 8 * (r >> 2) + hi4);
        oacc[0][r] *= alT;
        oacc[1][r] *= alT;
      }
    }

    // ---- p = exp2(s - m), pack -> PV A-frags (T12)
    s16x8 pa[2][2];
#pragma unroll
    for (int n = 0; n < 2; ++n) {
#pragma unroll
      for (int r = 0; r < 16; ++r) st[n][r] = EX2(st[n][r] - mr);
      float s01 = st[n][0] + st[n][1], s23 = st[n][2] + st[n][3];
      float s45 = st[n][4] + st[n][5], s67 = st[n][6] + st[n][7];
      float s89 = st[n][8] + st[n][9], sab = st[n][10] + st[n][11];
      float scd = st[n][12] + st[n][13], sef = st[n][14] + st[n][15];
      lr += ((s01 + s23) + (s45 + s67)) + ((s89 + sab) + (scd + sef));
      u32 x0 = cvtpk(st[n][0], st[n][1]);
      u32 x1 = cvtpk(st[n][2], st[n][3]);
      u32 x2 = cvtpk(st[n][4], st[n][5]);
      u32 x3 = cvtpk(st[n][6], st[n][7]);
      auto sA = __builtin_amdgcn_permlane32_swap(x0, x2, false, false);
      auto sB = __builtin_amdgcn_permlane32_swap(x1, x3, false, false);
      u32x4 w0 = {sA[0], sB[0], sA[1], sB[1]};
      pa[n][0] = __builtin_bit_cast(s16x8, w0);
      u32 x4 = cvtpk(st[n][8], st[n][9]);
      u32 x5 = cvtpk(st[n][10], st[n][11]);
      u32 x6 = cvtpk(st[n][12], st[n][13]);
      u32 x7 = cvtpk(st[n][14], st[n][15]);
      auto sC = __builtin_amdgcn_permlane32_swap(x4, x6, false, false);
      auto sD = __builtin_amdgcn_permlane32_swap(x5, x7, false, false);
      u32x4 w1 = {sC[0], sD[0], sC[1], sD[1]};
      pa[n][1] = __builtin_bit_cast(s16x8, w1);
    }

    // ---- O += P * V (in-register A-operand)
#pragma unroll
    for (int n = 0; n < 2; ++n)
#pragma unroll
      for (int kk2 = 0; kk2 < 2; ++kk2)
#pragma unroll
        for (int d0 = 0; d0 < 2; ++d0)
          oacc[d0] = __builtin_amdgcn_mfma_f32_32x32x16_bf16(pa[n][kk2], vf[n][kk2][d0], oacc[d0], 0, 0, 0);

    kfp += 4096;
    vfp += 4096;
    mpl += KVBLK;
  };

  s16x8 kA[2][4], kB[2][4];
  loadk(kA, kfp);
  for (int t = 0; t < ntw; t += 2) {
    step(kA, kB, t);
    if (t + 1 < ntw) step(kB, kA, t + 1);
  }

  // ---- epilogue: complete l across lane pair, normalize + store
  lr += __shfl_xor(lr, 32);
#pragma unroll
  for (int r = 0; r < 16; ++r) {
    int qoff = (r & 3) + 8 * (r >> 2) + hi4;
    float lq = __shfl(lr, qoff);
    float inv = lq > 0.f ? 1.f / lq : 0.f;
    size_t base = (size_t)(b * N_ + wq0 + qoff) * D_MODEL + h * DK + q32;
    Out[base] = f2b(oacc[0][r] * inv);
    Out[base + 32] = f2b(oacc[1][r] * inv);
  }
}

extern "C" void kernel_launch(void* const* d_in, const int* in_sizes, int n_in,
                              void* d_out, int out_size, void* d_ws, size_t ws_size,
                              hipStream_t stream) {
  const float* q = (const float*)d_in[0];
  const float* k = (const float*)d_in[1];
  const float* v = (const float*)d_in[2];
  const int* mask = (const int*)d_in[3];
  const float* Wq = (const float*)d_in[4];
  const float* Wk = (const float*)d_in[5];
  const float* Wv = (const float*)d_in[6];
  const float* Wo = (const float*)d_in[7];
  float* out = (float*)d_out;

  char* ws = (char*)d_ws;
  const size_t SZ = (size_t)M_TOT * D_MODEL * 2; // 16 MiB per bf16 [8192,1024]
  u16* qb = (u16*)ws;            // cvt(q); dead after attn (aliased below)
  u16* kb = (u16*)(ws + SZ);     // cvt(k); dead after K GEMM
  u16* vb = (u16*)(ws + 2 * SZ); // cvt(v); dead after V GEMM
  u16* Qf = (u16*)(ws + 3 * SZ);
  u16* Vf = (u16*)(ws + 4 * SZ);
  u16* Wqt = (u16*)(ws + 5 * SZ);
  u16* Wkt = Wqt + 1024 * 1024;
  u16* Wvt = Wkt + 1024 * 1024;
  u16* Wot = Wvt + 1024 * 1024;
  float* Mb = (float*)(Wot + 1024 * 1024);
  u16* Kf = (u16*)(ws + 5 * SZ + 4 * 2 * 1024 * 1024 + ((B_ * N_ * 4 + 255) & ~255));
  u16* attn_out = kb; // kb dead after gemm_qkv; attn writes here

  int n4 = M_TOT * D_MODEL / 4;
  cvt3_f32_bf16<<<dim3(n4 / 256, 3), 256, 0, stream>>>(q, k, v, qb, kb, vb, n4);
  mask_bias<<<(B_ * N_ + 255) / 256, 256, 0, stream>>>(mask, Mb, B_ * N_);
  wtrans4<<<dim3(32, 32, 4), 256, 0, stream>>>(Wq, Wk, Wv, Wo, Wqt, Wkt, Wvt, Wot);
  gemm_qkv<<<dim3(512, 3), 256, 0, stream>>>(qb, kb, vb, Wqt, Wkt, Wvt, Qf, Kf, Vf);
  attn_fwd<<<4096, 64, 0, stream>>>(Qf, Kf, Vf, Mb, attn_out);
  gemm_f32<<<512, 256, 0, stream>>>(attn_out, Wot, out);
}

// Round 21
// 207.922 us; speedup vs baseline: 1.6372x; 1.0799x over previous
//
#include <hip/hip_runtime.h>
#include <hip/hip_bf16.h>

typedef unsigned short u16;
typedef unsigned int u32;
typedef short s16x8 __attribute__((ext_vector_type(8)));
typedef float f32x4 __attribute__((ext_vector_type(4)));
typedef float f32x16 __attribute__((ext_vector_type(16)));
typedef u16 u16x4 __attribute__((ext_vector_type(4)));
typedef u32 u32x4 __attribute__((ext_vector_type(4)));

#define D_MODEL 1024
#define NHEAD 16
#define DK 64
#define B_ 4
#define N_ 2048
#define M_TOT (B_ * N_) /* 8192 */
#define QBLK 128
#define KVBLK 64
#define SCALE2 0.1803368801111137f /* 0.125 * log2(e) */
#define FRAG_PER_BH 131072 /* N_*DK elems per (b,h) */
#define EX2(x) __builtin_amdgcn_exp2f(x) /* raw v_exp_f32 */

__device__ __forceinline__ u16 f2b(float x) {
  __hip_bfloat16 h = __float2bfloat16(x);
  return __builtin_bit_cast(u16, h);
}

__device__ __forceinline__ u32 cvtpk(float lo, float hi) {
  u32 r;
  asm("v_cvt_pk_bf16_f32 %0, %1, %2" : "=v"(r) : "v"(lo), "v"(hi));
  return r;
}

__device__ __forceinline__ void gload_lds16(const void* gp, void* lp) {
  __builtin_amdgcn_global_load_lds(
      (const __attribute__((address_space(1))) unsigned int*)gp,
      (__attribute__((address_space(3))) unsigned int*)lp, 16, 0, 0);
}

// ---------------- fused elementwise f32 -> bf16 (q,k,v in one launch) -----
__global__ __launch_bounds__(256) void cvt3_f32_bf16(const float* __restrict__ x0,
                                                     const float* __restrict__ x1,
                                                     const float* __restrict__ x2,
                                                     u16* __restrict__ y0,
                                                     u16* __restrict__ y1,
                                                     u16* __restrict__ y2, int n4) {
  int z = blockIdx.y;
  const float* x = z == 0 ? x0 : (z == 1 ? x1 : x2);
  u16* y = z == 0 ? y0 : (z == 1 ? y1 : y2);
  int i = blockIdx.x * 256 + threadIdx.x;
  if (i < n4) {
    f32x4 v = *(const f32x4*)(x + (size_t)i * 4);
    u16x4 o;
    o[0] = f2b(v[0]); o[1] = f2b(v[1]); o[2] = f2b(v[2]); o[3] = f2b(v[3]);
    *(u16x4*)(y + (size_t)i * 4) = o;
  }
}

// ---------------- padding mask -> float bias (0 or -inf) ----------------
__global__ __launch_bounds__(256) void mask_bias(const int* __restrict__ mask,
                                                 float* __restrict__ Mb, int n) {
  int i = blockIdx.x * 256 + threadIdx.x;
  if (i < n) Mb[i] = mask[i] ? 0.f : -INFINITY;
}

// ------------- fused W transpose: 4 weights in one launch -------------
__global__ __launch_bounds__(256) void wtrans4(const float* __restrict__ W0,
                                               const float* __restrict__ W1,
                                               const float* __restrict__ W2,
                                               const float* __restrict__ W3,
                                               u16* __restrict__ T0,
                                               u16* __restrict__ T1,
                                               u16* __restrict__ T2,
                                               u16* __restrict__ T3) {
  __shared__ float tile[32][33];
  int z = blockIdx.z;
  const float* W = z == 0 ? W0 : (z == 1 ? W1 : (z == 2 ? W2 : W3));
  u16* Wt = z == 0 ? T0 : (z == 1 ? T1 : (z == 2 ? T2 : T3));
  int bi = blockIdx.y, bj = blockIdx.x;
  int tx = threadIdx.x & 31, ty = threadIdx.x >> 5; // 32 x 8
#pragma unroll
  for (int r = 0; r < 4; ++r)
    tile[ty + r * 8][tx] = W[(size_t)(bi * 32 + ty + r * 8) * D_MODEL + bj * 32 + tx];
  __syncthreads();
#pragma unroll
  for (int r = 0; r < 4; ++r)
    Wt[(size_t)(bj * 32 + ty + r * 8) * D_MODEL + bi * 32 + tx] = f2b(tile[tx][ty + r * 8]);
}

// ------------- GEMM body: C = A[8192,1024] * Bt[1024,1024]^T --------------
// XCD-local bi-rows (per-XCD WS = A-panel 2MB + B 2MB = L2).
// MODE 0: f32 row-major; MODE 1: bf16 fragment-major (K/Q layout);
// MODE 2: bf16 fragment-major (V layout).
template <int MODE>
__device__ __forceinline__ void gemm_body(const u16* __restrict__ A,
                                          const u16* __restrict__ Bt,
                                          float* __restrict__ Cf,
                                          u16* __restrict__ Cb) {
  const int N = D_MODEL, K = D_MODEL;
  __shared__ __align__(16) u16 Atile[128 * 32];
  __shared__ __align__(16) u16 Btile[128 * 32];
  int tid = threadIdx.x;
  int w = tid >> 6, lane = tid & 63;
  int g = lane >> 4, c = lane & 15;
  int wr = w >> 1, wc = w & 1;
  int bid = blockIdx.x;
  int xcd = bid & 7, idx = bid >> 3;
  int bi = xcd * 8 + (idx & 7);
  int bj = idx >> 3;
  const int rowA0 = bi * 128, rowB0 = bj * 128;

  const f32x4 fzero = {0.f, 0.f, 0.f, 0.f};
  f32x4 acc[4][4];
#pragma unroll
  for (int m = 0; m < 4; ++m)
#pragma unroll
    for (int n = 0; n < 4; ++n) acc[m][n] = fzero;

  for (int k0 = 0; k0 < K; k0 += 32) {
#pragma unroll
    for (int cc = 0; cc < 2; ++cc) {
      int li = w * 2 + cc;
      const u16* ga = A + (size_t)(rowA0 + li * 16 + (lane >> 2)) * K + k0 + (lane & 3) * 8;
      gload_lds16(ga, &Atile[li * 512]);
      const u16* gb = Bt + (size_t)(rowB0 + li * 16 + (lane >> 2)) * K + k0 + (lane & 3) * 8;
      gload_lds16(gb, &Btile[li * 512]);
    }
    __syncthreads();
    s16x8 af[4], bfr[4];
#pragma unroll
    for (int m = 0; m < 4; ++m)
      af[m] = *(const s16x8*)&Atile[(wr * 64 + m * 16 + c) * 32 + g * 8];
#pragma unroll
    for (int n = 0; n < 4; ++n)
      bfr[n] = *(const s16x8*)&Btile[(wc * 64 + n * 16 + c) * 32 + g * 8];
#pragma unroll
    for (int m = 0; m < 4; ++m)
#pragma unroll
      for (int n = 0; n < 4; ++n)
        acc[m][n] = __builtin_amdgcn_mfma_f32_16x16x32_bf16(af[m], bfr[n], acc[m][n], 0, 0, 0);
    __syncthreads();
  }

  if (MODE == 0) {
#pragma unroll
    for (int m = 0; m < 4; ++m)
#pragma unroll
      for (int n = 0; n < 4; ++n)
#pragma unroll
        for (int r = 0; r < 4; ++r) {
          int row = rowA0 + wr * 64 + m * 16 + g * 4 + r;
          int col = rowB0 + wc * 64 + n * 16 + c;
          Cf[(size_t)row * N + col] = acc[m][n][r];
        }
  } else if (MODE == 1) {
    // K/Q fragment layout: lane l holds X[f32*32+(l&31)][kk*16+(l>>5)*8+e]
    int bb = rowA0 >> 11;
    int hloc = bj * 2 + wc;
    size_t fb = ((size_t)bb * NHEAD + hloc) * FRAG_PER_BH;
#pragma unroll
    for (int m = 0; m < 4; ++m) {
      int rowm = rowA0 + wr * 64 + m * 16;
      size_t f32b = (size_t)((rowm & 2047) >> 5) * 4;
      int lpart = (m & 1) * 16 + g * 4 + (c >> 3) * 32;
#pragma unroll
      for (int n = 0; n < 4; ++n)
#pragma unroll
        for (int r = 0; r < 4; ++r)
          Cb[fb + (f32b + n) * 512 + (size_t)(lpart + r) * 8 + (c & 7)] = f2b(acc[m][n][r]);
    }
  } else {
    // V fragment layout: lane l holds V[kv16*16+(l>>5)*8+e][d0*32+(l&31)]
    int bb = rowA0 >> 11;
    int hloc = bj * 2 + wc;
    size_t fb = ((size_t)bb * NHEAD + hloc) * FRAG_PER_BH;
#pragma unroll
    for (int m = 0; m < 4; ++m) {
      int rowm = rowA0 + wr * 64 + m * 16; // +g*4+r < 16
      size_t kv16b = (size_t)((rowm & 2047) >> 4) * 2;
#pragma unroll
      for (int n = 0; n < 4; ++n) {
        size_t idxo = fb + (kv16b + (n >> 1)) * 512 +
                      (size_t)((n & 1) * 16 + c + (g >> 1) * 32) * 8 + (g & 1) * 4;
        u16x4 pv;
        pv[0] = f2b(acc[m][n][0]); pv[1] = f2b(acc[m][n][1]);
        pv[2] = f2b(acc[m][n][2]); pv[3] = f2b(acc[m][n][3]);
        *(u16x4*)&Cb[idxo] = pv;
      }
    }
  }
}

// fused Q/K/V projection: blockIdx.y picks operand set + epilogue layout
__global__ __launch_bounds__(256) void gemm_qkv(const u16* __restrict__ Aq,
                                                const u16* __restrict__ Ak,
                                                const u16* __restrict__ Av,
                                                const u16* __restrict__ Btq,
                                                const u16* __restrict__ Btk,
                                                const u16* __restrict__ Btv,
                                                u16* __restrict__ Cq,
                                                u16* __restrict__ Ck,
                                                u16* __restrict__ Cv) {
  int z = blockIdx.y;
  if (z == 0) gemm_body<1>(Aq, Btq, nullptr, Cq);
  else if (z == 1) gemm_body<1>(Ak, Btk, nullptr, Ck);
  else gemm_body<2>(Av, Btv, nullptr, Cv);
}

__global__ __launch_bounds__(256) void gemm_f32(const u16* __restrict__ A,
                                                const u16* __restrict__ Bt,
                                                float* __restrict__ C) {
  gemm_body<0>(A, Bt, C, nullptr);
}

#define MAX4(a, b, c, d) fmaxf(fmaxf(a, b), fmaxf(c, d))

// ------------- causal flash attention: 32x32 MFMA, fragment-major Q/K/V ---
// R19 (last passing) + ONE change: the causal-mask block runs ONLY on each
// wave's final step (dg literal folded per call site); all earlier steps
// need no causal mask (their kv <= wq0-1 < qq by coverage). Max-tracking /
// defer-max numerics identical to R19.
__global__ __launch_bounds__(64) void attn_fwd(const u16* __restrict__ Qf,
                                               const u16* __restrict__ Kf,
                                               const u16* __restrict__ Vf,
                                               const float* __restrict__ Mb,
                                               u16* __restrict__ Out) {
  int bid = blockIdx.x;
  int xcd = bid & 7;
  int inner = bid >> 3;       // 0..511
  int j = inner >> 6;         // head-within-XCD 0..7
  int rem = inner & 63;       // 0..63
  int qt = 15 - (rem >> 2);   // heavy tiles first
  int w = rem & 3;            // wave-slot 0..3
  int bh = xcd * 8 + j;       // 0..63
  int b = bh >> 4, h = bh & 15;
  int lane = threadIdx.x & 63;
  int q32 = lane & 31, hi = lane >> 5;
  int hi4 = hi * 4;

  int q0 = qt * QBLK;
  int wq0 = q0 + w * 32; // this wave's first q row
  int ntw = wq0 / KVBLK + 1;
  int qq = wq0 + q32;

  const u16* qfb0 = Qf + (size_t)(b * NHEAD + h) * FRAG_PER_BH + lane * 8;
  const u16* kfp = Kf + (size_t)(b * NHEAD + h) * FRAG_PER_BH + lane * 8;
  const u16* vfp = Vf + (size_t)(b * NHEAD + h) * FRAG_PER_BH + lane * 8;
  const float* mpl = Mb + (size_t)b * N_ + hi4;

  const f32x16 fz16 = {0.f, 0.f, 0.f, 0.f, 0.f, 0.f, 0.f, 0.f,
                       0.f, 0.f, 0.f, 0.f, 0.f, 0.f, 0.f, 0.f};

  // Q (B-operand) from fragment-major: frag group wq0/32, kk 0..3
  s16x8 qf[4];
#pragma unroll
  for (int kk = 0; kk < 4; ++kk)
    qf[kk] = *(const s16x8*)(qfb0 + ((size_t)((wq0 >> 5) * 4 + kk)) * 512);

  f32x16 oacc[2];
  oacc[0] = fz16; oacc[1] = fz16;
  float mr = -1e30f, lr = 0.f;

  auto loadk = [&](s16x8(&kf)[2][4], const u16* kp) {
#pragma unroll
    for (int n = 0; n < 2; ++n)
#pragma unroll
      for (int kk = 0; kk < 4; ++kk)
        kf[n][kk] = *(const s16x8*)(kp + (n * 4 + kk) * 512);
  };

  // dg passed as a literal at every call site -> causal block folds away
  auto step = [&](s16x8(&kc)[2][4], s16x8(&kn)[2][4], int t, bool dg) {
    int kv0 = t * KVBLK;
    // V + mask FIRST...
    s16x8 vf[2][2][2];
#pragma unroll
    for (int n = 0; n < 2; ++n)
#pragma unroll
      for (int kk2 = 0; kk2 < 2; ++kk2)
#pragma unroll
        for (int d0 = 0; d0 < 2; ++d0)
          vf[n][kk2][d0] = *(const s16x8*)(vfp + ((n * 2 + kk2) * 2 + d0) * 512);
    f32x4 mbv[2][4];
#pragma unroll
    for (int n = 0; n < 2; ++n)
#pragma unroll
      for (int jj = 0; jj < 4; ++jj)
        mbv[n][jj] = *(const f32x4*)(mpl + n * 32 + jj * 8);
    // ...K-prefetch LAST (stays in flight across the step)
    if (t + 1 < ntw) loadk(kn, kfp + 4096);

    // ---- S^T = K Q^T
    f32x16 st[2];
#pragma unroll
    for (int n = 0; n < 2; ++n) {
      f32x16 a = fz16;
      a = __builtin_amdgcn_mfma_f32_32x32x16_bf16(kc[n][0], qf[0], a, 0, 0, 0);
      a = __builtin_amdgcn_mfma_f32_32x32x16_bf16(kc[n][1], qf[1], a, 0, 0, 0);
      a = __builtin_amdgcn_mfma_f32_32x32x16_bf16(kc[n][2], qf[2], a, 0, 0, 0);
      a = __builtin_amdgcn_mfma_f32_32x32x16_bf16(kc[n][3], qf[3], a, 0, 0, 0);
      st[n] = a;
    }

    // ---- scale + padding bias (+ causal only when dg)
#pragma unroll
    for (int n = 0; n < 2; ++n)
#pragma unroll
      for (int r = 0; r < 16; ++r) {
        float v = fmaf(st[n][r], SCALE2, mbv[n][r >> 2][r & 3]);
        if (dg) {
          int kv = kv0 + n * 32 + (r & 3) + 8 * (r >> 2) + hi4;
          v = (kv > qq) ? -INFINITY : v;
        }
        st[n][r] = v;
      }
    float a0 = MAX4(st[0][0], st[0][1], st[0][2], st[0][3]);
    float a1 = MAX4(st[0][4], st[0][5], st[0][6], st[0][7]);
    float a2 = MAX4(st[0][8], st[0][9], st[0][10], st[0][11]);
    float a3 = MAX4(st[0][12], st[0][13], st[0][14], st[0][15]);
    float b0 = MAX4(st[1][0], st[1][1], st[1][2], st[1][3]);
    float b1 = MAX4(st[1][4], st[1][5], st[1][6], st[1][7]);
    float b2 = MAX4(st[1][8], st[1][9], st[1][10], st[1][11]);
    float b3 = MAX4(st[1][12], st[1][13], st[1][14], st[1][15]);
    float pmax = fmaxf(MAX4(a0, a1, a2, a3), MAX4(b0, b1, b2, b3));

    // ---- defer-max rescale (T13)
    if (__any(pmax > mr + 8.f)) {
      float pm2 = fmaxf(pmax, __shfl_xor(pmax, 32));
      float mnew = fmaxf(mr, pm2);
      float al = EX2(mr - mnew);
      mr = mnew;
      lr *= al;
#pragma unroll
      for (int r = 0; r < 16; ++r) {
        float alT = __shfl(al, (r & 3) + 8 * (r >> 2) + hi4);
        oacc[0][r] *= alT;
        oacc[1][r] *= alT;
      }
    }

    // ---- p = exp2(s - m), pack -> PV A-frags (T12)
    s16x8 pa[2][2];
#pragma unroll
    for (int n = 0; n < 2; ++n) {
#pragma unroll
      for (int r = 0; r < 16; ++r) st[n][r] = EX2(st[n][r] - mr);
      float s01 = st[n][0] + st[n][1], s23 = st[n][2] + st[n][3];
      float s45 = st[n][4] + st[n][5], s67 = st[n][6] + st[n][7];
      float s89 = st[n][8] + st[n][9], sab = st[n][10] + st[n][11];
      float scd = st[n][12] + st[n][13], sef = st[n][14] + st[n][15];
      lr += ((s01 + s23) + (s45 + s67)) + ((s89 + sab) + (scd + sef));
      u32 x0 = cvtpk(st[n][0], st[n][1]);
      u32 x1 = cvtpk(st[n][2], st[n][3]);
      u32 x2 = cvtpk(st[n][4], st[n][5]);
      u32 x3 = cvtpk(st[n][6], st[n][7]);
      auto sA = __builtin_amdgcn_permlane32_swap(x0, x2, false, false);
      auto sB = __builtin_amdgcn_permlane32_swap(x1, x3, false, false);
      u32x4 w0 = {sA[0], sB[0], sA[1], sB[1]};
      pa[n][0] = __builtin_bit_cast(s16x8, w0);
      u32 x4 = cvtpk(st[n][8], st[n][9]);
      u32 x5 = cvtpk(st[n][10], st[n][11]);
      u32 x6 = cvtpk(st[n][12], st[n][13]);
      u32 x7 = cvtpk(st[n][14], st[n][15]);
      auto sC = __builtin_amdgcn_permlane32_swap(x4, x6, false, false);
      auto sD = __builtin_amdgcn_permlane32_swap(x5, x7, false, false);
      u32x4 w1 = {sC[0], sD[0], sC[1], sD[1]};
      pa[n][1] = __builtin_bit_cast(s16x8, w1);
    }

    // ---- O += P * V (in-register A-operand)
#pragma unroll
    for (int n = 0; n < 2; ++n)
#pragma unroll
      for (int kk2 = 0; kk2 < 2; ++kk2)
#pragma unroll
        for (int d0 = 0; d0 < 2; ++d0)
          oacc[d0] = __builtin_amdgcn_mfma_f32_32x32x16_bf16(pa[n][kk2], vf[n][kk2][d0], oacc[d0], 0, 0, 0);

    kfp += 4096;
    vfp += 4096;
    mpl += KVBLK;
  };

  s16x8 kA[2][4], kB[2][4];
  loadk(kA, kfp);
  int nfull = ntw - 1; // all steps before the last are causal-free
  int t = 0;
  for (; t + 1 < nfull; t += 2) {
    step(kA, kB, t, false);
    step(kB, kA, t + 1, false);
  }
  if (t < nfull) { // t is even here
    step(kA, kB, t, false);
    ++t;
  }
  // final step (t == ntw-1): causal mask applies
  if (t & 1) step(kB, kA, t, true);
  else       step(kA, kB, t, true);

  // ---- epilogue: complete l across lane pair, normalize + store
  lr += __shfl_xor(lr, 32);
#pragma unroll
  for (int r = 0; r < 16; ++r) {
    int qoff = (r & 3) + 8 * (r >> 2) + hi4;
    float lq = __shfl(lr, qoff);
    float inv = lq > 0.f ? 1.f / lq : 0.f;
    size_t base = (size_t)(b * N_ + wq0 + qoff) * D_MODEL + h * DK + q32;
    Out[base] = f2b(oacc[0][r] * inv);
    Out[base + 32] = f2b(oacc[1][r] * inv);
  }
}

extern "C" void kernel_launch(void* const* d_in, const int* in_sizes, int n_in,
                              void* d_out, int out_size, void* d_ws, size_t ws_size,
                              hipStream_t stream) {
  const float* q = (const float*)d_in[0];
  const float* k = (const float*)d_in[1];
  const float* v = (const float*)d_in[2];
  const int* mask = (const int*)d_in[3];
  const float* Wq = (const float*)d_in[4];
  const float* Wk = (const float*)d_in[5];
  const float* Wv = (const float*)d_in[6];
  const float* Wo = (const float*)d_in[7];
  float* out = (float*)d_out;

  char* ws = (char*)d_ws;
  const size_t SZ = (size_t)M_TOT * D_MODEL * 2; // 16 MiB per bf16 [8192,1024]
  u16* qb = (u16*)ws;            // cvt(q); dead after gemm_qkv
  u16* kb = (u16*)(ws + SZ);     // cvt(k); dead after gemm_qkv
  u16* vb = (u16*)(ws + 2 * SZ); // cvt(v); dead after gemm_qkv
  u16* Qf = (u16*)(ws + 3 * SZ);
  u16* Vf = (u16*)(ws + 4 * SZ);
  u16* Wqt = (u16*)(ws + 5 * SZ);
  u16* Wkt = Wqt + 1024 * 1024;
  u16* Wvt = Wkt + 1024 * 1024;
  u16* Wot = Wvt + 1024 * 1024;
  float* Mb = (float*)(Wot + 1024 * 1024);
  u16* Kf = (u16*)(ws + 5 * SZ + 4 * 2 * 1024 * 1024 + ((B_ * N_ * 4 + 255) & ~255));
  u16* attn_out = kb; // kb dead after gemm_qkv; attn writes here

  int n4 = M_TOT * D_MODEL / 4;
  cvt3_f32_bf16<<<dim3(n4 / 256, 3), 256, 0, stream>>>(q, k, v, qb, kb, vb, n4);
  mask_bias<<<(B_ * N_ + 255) / 256, 256, 0, stream>>>(mask, Mb, B_ * N_);
  wtrans4<<<dim3(32, 32, 4), 256, 0, stream>>>(Wq, Wk, Wv, Wo, Wqt, Wkt, Wvt, Wot);
  gemm_qkv<<<dim3(512, 3), 256, 0, stream>>>(qb, kb, vb, Wqt, Wkt, Wvt, Qf, Kf, Vf);
  attn_fwd<<<4096, 64, 0, stream>>>(Qf, Kf, Vf, Mb, attn_out);
  gemm_f32<<<512, 256, 0, stream>>>(attn_out, Wot, out);
}